// Round 1
// baseline (1187.613 us; speedup 1.0000x reference)
//
#include <hip/hip_runtime.h>

#define NN 8192
#define FIN 1024
#define FOUT 512

// ---------------- Kernel 1: d_is = 1/sqrt(rowsum(adj)+1) ----------------
__global__ __launch_bounds__(256) void rowsum_kernel(const float* __restrict__ adj,
                                                     float* __restrict__ d_is) {
    const int row = blockIdx.x;
    const float4* a = reinterpret_cast<const float4*>(adj + (size_t)row * NN);
    float s = 0.f;
    #pragma unroll 4
    for (int j = threadIdx.x; j < NN / 4; j += 256) {
        float4 v = a[j];
        s += (v.x + v.y) + (v.z + v.w);
    }
    #pragma unroll
    for (int off = 32; off > 0; off >>= 1) s += __shfl_down(s, off, 64);
    __shared__ float red[4];
    const int lane = threadIdx.x & 63;
    const int wv = threadIdx.x >> 6;
    if (lane == 0) red[wv] = s;
    __syncthreads();
    if (threadIdx.x == 0) {
        const float d = red[0] + red[1] + red[2] + red[3] + 1.0f; // +1: self loop
        d_is[row] = 1.0f / sqrtf(d);
    }
}

// ---------------- Kernel 2/3: 64x64-tile f32 GEMM ----------------
// FINAL=false: C[r,c] = d_is[r] * (A@B)[r,c]           (ps = D^{-1/2} x W)
// FINAL=true : C[r,c] = relu(d_is[r]*((A@B)[r,c] + B[r,c]) + bias[c])
template<int K, int N, bool FINAL>
__global__ __launch_bounds__(256) void gemm64_kernel(const float* __restrict__ A,
                                                     const float* __restrict__ B,
                                                     const float* __restrict__ d_is,
                                                     const float* __restrict__ bias,
                                                     float* __restrict__ C) {
    constexpr int TILE = 64;
    constexpr int KT = 16;
    __shared__ float As[KT][TILE + 4];
    __shared__ float Bs[KT][TILE + 4];

    const int tid = threadIdx.x;
    const int tx = tid & 15;   // col group: cols tx*4..tx*4+3
    const int ty = tid >> 4;   // row group: rows ty*4..ty*4+3
    const int row0 = blockIdx.y * TILE;
    const int col0 = blockIdx.x * TILE;

    const int la_r = tid >> 4;   // 0..15 (+16*l)
    const int la_k = tid & 15;   // 0..15
    const int lb_c = tid & 63;   // 0..63
    const int lb_k = tid >> 6;   // 0..3 (+4*l)

    float acc[4][4] = {};

    for (int k0 = 0; k0 < K; k0 += KT) {
        #pragma unroll
        for (int l = 0; l < 4; ++l) {
            const int r = la_r + l * 16;
            As[la_k][r] = A[(size_t)(row0 + r) * K + (k0 + la_k)];
        }
        #pragma unroll
        for (int l = 0; l < 4; ++l) {
            const int kk = lb_k + l * 4;
            Bs[kk][lb_c] = B[(size_t)(k0 + kk) * N + (col0 + lb_c)];
        }
        __syncthreads();
        #pragma unroll
        for (int kk = 0; kk < KT; ++kk) {
            const float4 av = *reinterpret_cast<const float4*>(&As[kk][ty * 4]);
            const float4 bv = *reinterpret_cast<const float4*>(&Bs[kk][tx * 4]);
            const float a4[4] = {av.x, av.y, av.z, av.w};
            const float b4[4] = {bv.x, bv.y, bv.z, bv.w};
            #pragma unroll
            for (int i = 0; i < 4; ++i)
                #pragma unroll
                for (int j = 0; j < 4; ++j)
                    acc[i][j] += a4[i] * b4[j];
        }
        __syncthreads();
    }

    #pragma unroll
    for (int i = 0; i < 4; ++i) {
        const int grow = row0 + ty * 4 + i;
        const int gcol = col0 + tx * 4;
        const float dr = d_is[grow];
        float4 o;
        if (FINAL) {
            const float4 self = *reinterpret_cast<const float4*>(&B[(size_t)grow * N + gcol]);
            const float4 bb = *reinterpret_cast<const float4*>(&bias[gcol]);
            o.x = fmaxf(dr * (acc[i][0] + self.x) + bb.x, 0.f);
            o.y = fmaxf(dr * (acc[i][1] + self.y) + bb.y, 0.f);
            o.z = fmaxf(dr * (acc[i][2] + self.z) + bb.z, 0.f);
            o.w = fmaxf(dr * (acc[i][3] + self.w) + bb.w, 0.f);
        } else {
            o.x = dr * acc[i][0];
            o.y = dr * acc[i][1];
            o.z = dr * acc[i][2];
            o.w = dr * acc[i][3];
        }
        *reinterpret_cast<float4*>(&C[(size_t)grow * N + gcol]) = o;
    }
}

extern "C" void kernel_launch(void* const* d_in, const int* in_sizes, int n_in,
                              void* d_out, int out_size, void* d_ws, size_t ws_size,
                              hipStream_t stream) {
    const float* x   = (const float*)d_in[0];
    const float* adj = (const float*)d_in[1];
    const float* W   = (const float*)d_in[2];
    const float* b   = (const float*)d_in[3];
    float* out = (float*)d_out;

    float* ps  = (float*)d_ws;                  // [NN, FOUT] = 16 MB scratch
    float* dis = ps + (size_t)NN * FOUT;        // [NN] = 32 KB

    hipLaunchKernelGGL(rowsum_kernel, dim3(NN), dim3(256), 0, stream, adj, dis);
    hipLaunchKernelGGL((gemm64_kernel<FIN, FOUT, false>),
                       dim3(FOUT / 64, NN / 64), dim3(256), 0, stream, x, W, dis, b, ps);
    hipLaunchKernelGGL((gemm64_kernel<NN, FOUT, true>),
                       dim3(FOUT / 64, NN / 64), dim3(256), 0, stream, adj, ps, dis, b, out);
}

// Round 2
// 482.286 us; speedup vs baseline: 2.4625x; 2.4625x over previous
//
#include <hip/hip_runtime.h>
#include <stdint.h>

#define NN 8192
#define FIN 1024
#define FOUT 512

typedef __attribute__((ext_vector_type(4))) float f32x4;
typedef __attribute__((ext_vector_type(8))) short s16x8;
typedef __attribute__((ext_vector_type(4))) unsigned short u16x4;

__device__ __forceinline__ short f2bf(float f) {
    return __builtin_bit_cast(short, static_cast<__bf16>(f));
}
__device__ __forceinline__ float bf2f(short s) {
    return static_cast<float>(__builtin_bit_cast(__bf16, s));
}

// ---------------- Kernel 1: d_is = 1/sqrt(rowsum(adj)+1) ----------------
__global__ __launch_bounds__(256) void rowsum_kernel(const float* __restrict__ adj,
                                                     float* __restrict__ d_is) {
    const int row = blockIdx.x;
    const float4* a = reinterpret_cast<const float4*>(adj + (size_t)row * NN);
    float s = 0.f;
    #pragma unroll 4
    for (int j = threadIdx.x; j < NN / 4; j += 256) {
        float4 v = a[j];
        s += (v.x + v.y) + (v.z + v.w);
    }
    #pragma unroll
    for (int off = 32; off > 0; off >>= 1) s += __shfl_down(s, off, 64);
    __shared__ float red[4];
    const int lane = threadIdx.x & 63;
    const int wv = threadIdx.x >> 6;
    if (lane == 0) red[wv] = s;
    __syncthreads();
    if (threadIdx.x == 0) {
        const float d = red[0] + red[1] + red[2] + red[3] + 1.0f; // +1: self loop
        d_is[row] = 1.0f / sqrtf(d);
    }
}

// ---------------- Kernel 2: psT[c][r] = bf16(d_is[r] * (x@W)[r][c]) ----------------
__global__ __launch_bounds__(256) void xw_kernel(const float* __restrict__ A,
                                                 const float* __restrict__ B,
                                                 const float* __restrict__ d_is,
                                                 short* __restrict__ psT) {
    constexpr int K = FIN, N = FOUT;
    constexpr int TILE = 64;
    constexpr int KT = 16;
    __shared__ float As[KT][TILE + 4];
    __shared__ float Bs[KT][TILE + 4];

    const int tid = threadIdx.x;
    const int tx = tid & 15;
    const int ty = tid >> 4;
    const int row0 = blockIdx.y * TILE;
    const int col0 = blockIdx.x * TILE;

    const int la_r = tid >> 4;
    const int la_k = tid & 15;
    const int lb_c = tid & 63;
    const int lb_k = tid >> 6;

    float acc[4][4] = {};

    for (int k0 = 0; k0 < K; k0 += KT) {
        #pragma unroll
        for (int l = 0; l < 4; ++l) {
            const int r = la_r + l * 16;
            As[la_k][r] = A[(size_t)(row0 + r) * K + (k0 + la_k)];
        }
        #pragma unroll
        for (int l = 0; l < 4; ++l) {
            const int kk = lb_k + l * 4;
            Bs[kk][lb_c] = B[(size_t)(k0 + kk) * N + (col0 + lb_c)];
        }
        __syncthreads();
        #pragma unroll
        for (int kk = 0; kk < KT; ++kk) {
            const float4 av = *reinterpret_cast<const float4*>(&As[kk][ty * 4]);
            const float4 bv = *reinterpret_cast<const float4*>(&Bs[kk][tx * 4]);
            const float a4[4] = {av.x, av.y, av.z, av.w};
            const float b4[4] = {bv.x, bv.y, bv.z, bv.w};
            #pragma unroll
            for (int i = 0; i < 4; ++i)
                #pragma unroll
                for (int j = 0; j < 4; ++j)
                    acc[i][j] += a4[i] * b4[j];
        }
        __syncthreads();
    }

    const int gcol = col0 + tx * 4;
    const int grow0 = row0 + ty * 4;
    float dr[4];
    #pragma unroll
    for (int i = 0; i < 4; ++i) dr[i] = d_is[grow0 + i];
    #pragma unroll
    for (int j = 0; j < 4; ++j) {
        u16x4 p;
        #pragma unroll
        for (int i = 0; i < 4; ++i)
            p[i] = (unsigned short)f2bf(dr[i] * acc[i][j]);
        *reinterpret_cast<u16x4*>(&psT[(size_t)(gcol + j) * NN + grow0]) = p;
    }
}

// ---------------- Kernel 3: out = relu(d_r*(adj@ps + ps) + b), bf16 MFMA ----------------
// A = adj [8192 x 8192] fp32 (converted on the fly), B = psT [512][8192] bf16 ([N][K]).
__global__ __launch_bounds__(256) void prop_kernel(const float* __restrict__ adj,
                                                   const short* __restrict__ psT,
                                                   const float* __restrict__ d_is,
                                                   const float* __restrict__ bias,
                                                   float* __restrict__ out) {
    __shared__ short As[2][128 * 32];
    __shared__ short Bs[2][128 * 32];

    const int tid = threadIdx.x;

    // chunked XCD swizzle: 256 blocks = 8 XCDs x 32; the 4 col-blocks of a
    // row-panel land on the same XCD -> adj panel fetched ~once.
    const int lin = blockIdx.y * 4 + blockIdx.x;
    const int swz = (lin & 7) * 32 + (lin >> 3);
    const int col0 = (swz & 3) * 128;
    const int row0 = (swz >> 2) * 128;

    const int lane = tid & 63;
    const int wv = tid >> 6;
    const int wr = wv >> 1;   // wave row 0..1  (64 rows each)
    const int wc = wv & 1;    // wave col 0..1  (64 cols each)
    const int l15 = lane & 15;
    const int koff = (lane >> 4) * 8;

    // A staging: thread t -> row t>>1, k-half (t&1)*16 (16 fp32 = 64B contig)
    const int ar = tid >> 1;
    const int ak = (tid & 1) * 16;
    const float* abase = adj + (size_t)(row0 + ar) * NN + ak;

    float4 q0, q1, q2, q3;
    auto loadA = [&](int k0) {
        const float4* p = reinterpret_cast<const float4*>(abase + k0);
        q0 = p[0]; q1 = p[1]; q2 = p[2]; q3 = p[3];
    };
    auto writeA = [&](int buf) {
        const float a[16] = {q0.x, q0.y, q0.z, q0.w, q1.x, q1.y, q1.z, q1.w,
                             q2.x, q2.y, q2.z, q2.w, q3.x, q3.y, q3.z, q3.w};
        s16x8 v0, v1;
        #pragma unroll
        for (int e = 0; e < 8; ++e) { v0[e] = f2bf(a[e]); v1[e] = f2bf(a[8 + e]); }
        *reinterpret_cast<s16x8*>(&As[buf][ar * 32 + ak]) = v0;
        *reinterpret_cast<s16x8*>(&As[buf][ar * 32 + ak + 8]) = v1;
    };
    auto gldsB = [&](int buf, int k0) {
        #pragma unroll
        for (int i = 0; i < 2; ++i) {
            const int slot = i * 256 + tid;
            const short* g = psT + (size_t)(col0 + (slot >> 2)) * NN + k0 + (slot & 3) * 8;
            short* dst = &Bs[buf][(i * 256 + (tid & 192)) * 8];  // wave-uniform base
            __builtin_amdgcn_global_load_lds(
                (const __attribute__((address_space(1))) unsigned int*)g,
                (__attribute__((address_space(3))) unsigned int*)dst, 16, 0, 0);
        }
    };

    f32x4 acc[4][4] = {};

    auto compute = [&](int buf) {
        s16x8 af[4], bfr[4];
        #pragma unroll
        for (int m = 0; m < 4; ++m)
            af[m] = *reinterpret_cast<const s16x8*>(&As[buf][(wr * 64 + m * 16 + l15) * 32 + koff]);
        #pragma unroll
        for (int n = 0; n < 4; ++n)
            bfr[n] = *reinterpret_cast<const s16x8*>(&Bs[buf][(wc * 64 + n * 16 + l15) * 32 + koff]);
        #pragma unroll
        for (int m = 0; m < 4; ++m)
            #pragma unroll
            for (int n = 0; n < 4; ++n)
                acc[m][n] = __builtin_amdgcn_mfma_f32_16x16x32_bf16(af[m], bfr[n], acc[m][n], 0, 0, 0);
    };

    // prologue
    loadA(0);
    writeA(0);
    gldsB(0, 0);
    __syncthreads();

    int cur = 0;
    constexpr int NT = NN / 32;  // 256
    for (int t = 0; t < NT; ++t) {
        const int kn = (t + 1) * 32;
        if (t < NT - 1) {
            loadA(kn);            // issue A-next global loads (to regs)
            gldsB(cur ^ 1, kn);   // issue B-next direct-to-LDS
        }
        compute(cur);             // ds_read + 16 MFMA on current buffers
        if (t < NT - 1) writeA(cur ^ 1);  // cvt + ds_write A-next
        __syncthreads();
        cur ^= 1;
    }

    // epilogue: out[r][c] = relu(d_r*(S + psT[c][r]) + b[c])
    #pragma unroll
    for (int n = 0; n < 4; ++n) {
        const int col = col0 + wc * 64 + n * 16 + l15;
        const float bb = bias[col];
        #pragma unroll
        for (int m = 0; m < 4; ++m) {
            const int rbase = row0 + wr * 64 + m * 16 + (lane >> 4) * 4;
            #pragma unroll
            for (int j = 0; j < 4; ++j) {
                const int row = rbase + j;
                const float self = bf2f(psT[(size_t)col * NN + row]);
                const float o = d_is[row] * (acc[m][n][j] + self) + bb;
                out[(size_t)row * FOUT + col] = fmaxf(o, 0.f);
            }
        }
    }
}

extern "C" void kernel_launch(void* const* d_in, const int* in_sizes, int n_in,
                              void* d_out, int out_size, void* d_ws, size_t ws_size,
                              hipStream_t stream) {
    const float* x   = (const float*)d_in[0];
    const float* adj = (const float*)d_in[1];
    const float* W   = (const float*)d_in[2];
    const float* b   = (const float*)d_in[3];
    float* out = (float*)d_out;

    short* psT = (short*)d_ws;                          // [FOUT][NN] bf16 = 8 MB
    float* dis = (float*)(psT + (size_t)FOUT * NN);     // [NN] = 32 KB

    hipLaunchKernelGGL(rowsum_kernel, dim3(NN), dim3(256), 0, stream, adj, dis);
    hipLaunchKernelGGL(xw_kernel, dim3(FOUT / 64, NN / 64), dim3(256), 0, stream,
                       x, W, dis, psT);
    hipLaunchKernelGGL(prop_kernel, dim3(4, 64), dim3(256), 0, stream,
                       adj, psT, dis, b, out);
}

// Round 3
// 324.681 us; speedup vs baseline: 3.6578x; 1.4854x over previous
//
#include <hip/hip_runtime.h>
#include <stdint.h>

#define NN 8192
#define FIN 1024
#define FOUT 512

typedef __attribute__((ext_vector_type(4))) float f32x4;
typedef __attribute__((ext_vector_type(8))) short s16x8;
typedef __attribute__((ext_vector_type(4))) unsigned short u16x4;

__device__ __forceinline__ short f2bf(float f) {
    return __builtin_bit_cast(short, static_cast<__bf16>(f));
}
__device__ __forceinline__ float bf2f(short s) {
    return (float)__builtin_bit_cast(__bf16, s);
}

// ---------------- Kernel 1: d_is = 1/sqrt(rowsum(adj)+1) ----------------
__global__ __launch_bounds__(256) void rowsum_kernel(const float* __restrict__ adj,
                                                     float* __restrict__ d_is) {
    const int row = blockIdx.x;
    const float4* a = reinterpret_cast<const float4*>(adj + (size_t)row * NN);
    float s = 0.f;
    #pragma unroll 4
    for (int j = threadIdx.x; j < NN / 4; j += 256) {
        float4 v = a[j];
        s += (v.x + v.y) + (v.z + v.w);
    }
    #pragma unroll
    for (int off = 32; off > 0; off >>= 1) s += __shfl_down(s, off, 64);
    __shared__ float red[4];
    const int lane = threadIdx.x & 63;
    const int wv = threadIdx.x >> 6;
    if (lane == 0) red[wv] = s;
    __syncthreads();
    if (threadIdx.x == 0) {
        const float d = red[0] + red[1] + red[2] + red[3] + 1.0f; // +1: self loop
        d_is[row] = 1.0f / sqrtf(d);
    }
}

// ---------------- Kernel 2: WT[c][k] = bf16(W[k][c]) ----------------
__global__ __launch_bounds__(256) void wt_kernel(const float* __restrict__ W,
                                                 short* __restrict__ WT) {
    __shared__ float T[64][68];
    const int wc = blockIdx.x;  // tile over W cols (8)
    const int wk = blockIdx.y;  // tile over W rows (16)
    const int t = threadIdx.x;
    const int cc = (t & 15) * 4;
    #pragma unroll
    for (int i = 0; i < 4; ++i) {
        const int rr = (t >> 4) + i * 16;
        *reinterpret_cast<float4*>(&T[rr][cc]) =
            *reinterpret_cast<const float4*>(&W[(size_t)(wk * 64 + rr) * FOUT + wc * 64 + cc]);
    }
    __syncthreads();
    const int a = t >> 2;         // WT row within tile (= W col)
    const int b0 = (t & 3) * 16;  // WT col chunk (= W row)
    s16x8 v0, v1;
    #pragma unroll
    for (int e = 0; e < 8; ++e) { v0[e] = f2bf(T[b0 + e][a]); v1[e] = f2bf(T[b0 + 8 + e][a]); }
    short* dst = &WT[(size_t)(wc * 64 + a) * FIN + wk * 64 + b0];
    *reinterpret_cast<s16x8*>(dst) = v0;
    *reinterpret_cast<s16x8*>(dst + 8) = v1;
}

// ---------------- Kernel 3: generic bf16-MFMA GEMM, 128x64 tile, BK=32 ----------------
// A [8192][KLEN] f32 (cvt on the fly), B [512][KLEN] bf16 (B^T layout).
// MODE 0 (xw):  psT[col][row] = bf16(d_is[row] * acc)           (KS=1)
// MODE 1 (prop): raw f32 partial -> (ks==0 ? P0 (+self term) : P1)  (KS=2)
template<int KLEN, int MODE>
__global__ __launch_bounds__(256, 4) void gemm_kernel(
    const float* __restrict__ A, const short* __restrict__ B,
    const float* __restrict__ d_is,
    short* __restrict__ psT,
    float* __restrict__ P0, float* __restrict__ P1) {
    constexpr int KS = (MODE == 1) ? 2 : 1;
    constexpr int Ksub = KLEN / KS;
    constexpr int NT = Ksub / 32;
    constexpr int LDA = 40;  // padded stride: 80 B -> 2-way bank aliasing (free)
    __shared__ short As[2][128 * LDA];
    __shared__ short Bs[2][64 * LDA];

    const int tid = threadIdx.x;
    // chunked XCD swizzle: each XCD gets contiguous row-panels (A panel L2-hot)
    const int nchunk = gridDim.x >> 3;
    const int lin = blockIdx.x;
    const int swz = (lin & 7) * nchunk + (lin >> 3);
    const int col0 = (swz & 7) * 64;
    const int yp = (swz >> 3) & 63;
    const int ks = swz >> 9;
    const int row0 = yp * 128;
    const int kbase = ks * Ksub;

    const int lane = tid & 63;
    const int wv = tid >> 6;
    const int wr = wv >> 1, wc = wv & 1;  // 2x2 waves, wave tile 64x32
    const int l15 = lane & 15;
    const int koff = (lane >> 4) * 8;

    const int ar = tid >> 1, ak = (tid & 1) * 16;
    const float* Abase = A + (size_t)(row0 + ar) * KLEN + kbase + ak;
    const int br = tid >> 2, bk = (tid & 3) * 8;
    const short* Bbase = B + (size_t)(col0 + br) * KLEN + kbase + bk;

    float4 qa0, qa1, qa2, qa3;
    s16x8 qb;
    auto loadG = [&](int k0) {
        const float4* p = reinterpret_cast<const float4*>(Abase + k0);
        qa0 = p[0]; qa1 = p[1]; qa2 = p[2]; qa3 = p[3];
        qb = *reinterpret_cast<const s16x8*>(Bbase + k0);
    };
    auto writeL = [&](int buf) {
        const float a[16] = {qa0.x, qa0.y, qa0.z, qa0.w, qa1.x, qa1.y, qa1.z, qa1.w,
                             qa2.x, qa2.y, qa2.z, qa2.w, qa3.x, qa3.y, qa3.z, qa3.w};
        s16x8 v0, v1;
        #pragma unroll
        for (int e = 0; e < 8; ++e) { v0[e] = f2bf(a[e]); v1[e] = f2bf(a[8 + e]); }
        *reinterpret_cast<s16x8*>(&As[buf][ar * LDA + ak]) = v0;
        *reinterpret_cast<s16x8*>(&As[buf][ar * LDA + ak + 8]) = v1;
        *reinterpret_cast<s16x8*>(&Bs[buf][br * LDA + bk]) = qb;
    };

    f32x4 acc[4][2] = {};
    auto compute = [&](int buf) {
        s16x8 af[4], bfr[2];
        #pragma unroll
        for (int m = 0; m < 4; ++m)
            af[m] = *reinterpret_cast<const s16x8*>(&As[buf][(wr * 64 + m * 16 + l15) * LDA + koff]);
        #pragma unroll
        for (int n = 0; n < 2; ++n)
            bfr[n] = *reinterpret_cast<const s16x8*>(&Bs[buf][(wc * 32 + n * 16 + l15) * LDA + koff]);
        #pragma unroll
        for (int m = 0; m < 4; ++m)
            #pragma unroll
            for (int n = 0; n < 2; ++n)
                acc[m][n] = __builtin_amdgcn_mfma_f32_16x16x32_bf16(af[m], bfr[n], acc[m][n], 0, 0, 0);
    };

    loadG(0);
    writeL(0);
    __syncthreads();
    int cur = 0;
    for (int t = 0; t < NT; ++t) {
        if (t + 1 < NT) loadG((t + 1) * 32);   // issue next-tile loads early
        compute(cur);                           // ds_read + 8 MFMA
        if (t + 1 < NT) writeL(cur ^ 1);        // cvt + ds_write after compute
        __syncthreads();
        cur ^= 1;
    }

    if (MODE == 0) {
        #pragma unroll
        for (int m = 0; m < 4; ++m) {
            const int rbase = row0 + wr * 64 + m * 16 + (lane >> 4) * 4;
            float dr[4];
            #pragma unroll
            for (int j = 0; j < 4; ++j) dr[j] = d_is[rbase + j];
            #pragma unroll
            for (int n = 0; n < 2; ++n) {
                const int col = col0 + wc * 32 + n * 16 + l15;
                u16x4 pk;
                #pragma unroll
                for (int j = 0; j < 4; ++j) pk[j] = (unsigned short)f2bf(dr[j] * acc[m][n][j]);
                *reinterpret_cast<u16x4*>(&psT[(size_t)col * NN + rbase]) = pk;
            }
        }
    } else {
        float* tgt = (ks == 0) ? P0 : P1;
        #pragma unroll
        for (int m = 0; m < 4; ++m) {
            const int rbase = row0 + wr * 64 + m * 16 + (lane >> 4) * 4;
            #pragma unroll
            for (int n = 0; n < 2; ++n) {
                const int col = col0 + wc * 32 + n * 16 + l15;
                f32x4 v = acc[m][n];
                if (ks == 0) {  // fold self-loop term once
                    const u16x4 sv = *reinterpret_cast<const u16x4*>(&psT[(size_t)col * NN + rbase]);
                    #pragma unroll
                    for (int j = 0; j < 4; ++j) v[j] += bf2f((short)sv[j]);
                }
                #pragma unroll
                for (int j = 0; j < 4; ++j)
                    tgt[(size_t)(rbase + j) * FOUT + col] = v[j];
            }
        }
    }
}

// ---------------- Kernel 4: out = relu(d_r*(P0+P1) + b) ----------------
__global__ __launch_bounds__(256) void ep_kernel(const float* __restrict__ P0,
                                                 float* __restrict__ out,
                                                 const float* __restrict__ d_is,
                                                 const float* __restrict__ bias) {
    const size_t idx = ((size_t)blockIdx.x * 256 + threadIdx.x) * 4;
    const int row = (int)(idx >> 9);
    const int col = (int)(idx & 511);
    const float4 p0 = *reinterpret_cast<const float4*>(&P0[idx]);
    const float4 p1 = *reinterpret_cast<const float4*>(&out[idx]);
    const float4 bb = *reinterpret_cast<const float4*>(&bias[col]);
    const float dr = d_is[row];
    float4 o;
    o.x = fmaxf(dr * (p0.x + p1.x) + bb.x, 0.f);
    o.y = fmaxf(dr * (p0.y + p1.y) + bb.y, 0.f);
    o.z = fmaxf(dr * (p0.z + p1.z) + bb.z, 0.f);
    o.w = fmaxf(dr * (p0.w + p1.w) + bb.w, 0.f);
    *reinterpret_cast<float4*>(&out[idx]) = o;
}

extern "C" void kernel_launch(void* const* d_in, const int* in_sizes, int n_in,
                              void* d_out, int out_size, void* d_ws, size_t ws_size,
                              hipStream_t stream) {
    const float* x   = (const float*)d_in[0];
    const float* adj = (const float*)d_in[1];
    const float* W   = (const float*)d_in[2];
    const float* b   = (const float*)d_in[3];
    float* out = (float*)d_out;

    short* psT = (short*)d_ws;                        // [512][8192] bf16 = 8 MB
    short* WT  = psT + (size_t)FOUT * NN;             // [512][1024] bf16 = 1 MB
    float* P0  = (float*)(WT + (size_t)FOUT * FIN);   // [8192][512] f32 = 16 MB
    float* dis = P0 + (size_t)NN * FOUT;              // [8192] f32

    hipLaunchKernelGGL(rowsum_kernel, dim3(NN), dim3(256), 0, stream, adj, dis);
    hipLaunchKernelGGL(wt_kernel, dim3(8, 16), dim3(256), 0, stream, W, WT);
    hipLaunchKernelGGL((gemm_kernel<FIN, 0>), dim3(512), dim3(256), 0, stream,
                       x, WT, dis, psT, nullptr, nullptr);
    hipLaunchKernelGGL((gemm_kernel<NN, 1>), dim3(1024), dim3(256), 0, stream,
                       adj, psT, dis, psT, P0, out);
    hipLaunchKernelGGL(ep_kernel, dim3(NN * FOUT / 1024), dim3(256), 0, stream,
                       P0, out, dis, b);
}

// Round 4
// 244.104 us; speedup vs baseline: 4.8652x; 1.3301x over previous
//
#include <hip/hip_runtime.h>
#include <stdint.h>

#define NN 8192
#define FIN 1024
#define FOUT 512

typedef __attribute__((ext_vector_type(4))) float f32x4;
typedef __attribute__((ext_vector_type(8))) short s16x8;
typedef __attribute__((ext_vector_type(4))) unsigned short u16x4;

__device__ __forceinline__ short f2bf(float f) {
    return __builtin_bit_cast(short, static_cast<__bf16>(f));
}
__device__ __forceinline__ float bf2f(short s) {
    return (float)__builtin_bit_cast(__bf16, s);
}

// ---------- Kernel 1A: d_is = 1/sqrt(rowsum+1)  AND  adjB = bf16(adj) ----------
__global__ __launch_bounds__(256) void rowsum_cvt_kernel(const float* __restrict__ adj,
                                                         short* __restrict__ adjB,
                                                         float* __restrict__ d_is) {
    const int row = blockIdx.x;
    const float4* a = reinterpret_cast<const float4*>(adj + (size_t)row * NN);
    u16x4* ob = reinterpret_cast<u16x4*>(adjB + (size_t)row * NN);
    float s = 0.f;
    #pragma unroll 2
    for (int j = threadIdx.x; j < NN / 4; j += 256) {
        float4 v = a[j];
        s += (v.x + v.y) + (v.z + v.w);
        u16x4 p;
        p[0] = (unsigned short)f2bf(v.x); p[1] = (unsigned short)f2bf(v.y);
        p[2] = (unsigned short)f2bf(v.z); p[3] = (unsigned short)f2bf(v.w);
        ob[j] = p;
    }
    #pragma unroll
    for (int off = 32; off > 0; off >>= 1) s += __shfl_down(s, off, 64);
    __shared__ float red[4];
    if ((threadIdx.x & 63) == 0) red[threadIdx.x >> 6] = s;
    __syncthreads();
    if (threadIdx.x == 0) {
        const float d = red[0] + red[1] + red[2] + red[3] + 1.0f;
        d_is[row] = 1.0f / sqrtf(d);
    }
}

// ---------- Kernel 1B (fallback path): rowsum only ----------
__global__ __launch_bounds__(256) void rowsum_kernel(const float* __restrict__ adj,
                                                     float* __restrict__ d_is) {
    const int row = blockIdx.x;
    const float4* a = reinterpret_cast<const float4*>(adj + (size_t)row * NN);
    float s = 0.f;
    #pragma unroll 4
    for (int j = threadIdx.x; j < NN / 4; j += 256) {
        float4 v = a[j];
        s += (v.x + v.y) + (v.z + v.w);
    }
    #pragma unroll
    for (int off = 32; off > 0; off >>= 1) s += __shfl_down(s, off, 64);
    __shared__ float red[4];
    if ((threadIdx.x & 63) == 0) red[threadIdx.x >> 6] = s;
    __syncthreads();
    if (threadIdx.x == 0) {
        const float d = red[0] + red[1] + red[2] + red[3] + 1.0f;
        d_is[row] = 1.0f / sqrtf(d);
    }
}

// ---------- Kernel 2: WT[c][k] = bf16(W[k][c]) ----------
__global__ __launch_bounds__(256) void wt_kernel(const float* __restrict__ W,
                                                 short* __restrict__ WT) {
    __shared__ float T[64][68];
    const int wc = blockIdx.x;
    const int wk = blockIdx.y;
    const int t = threadIdx.x;
    const int cc = (t & 15) * 4;
    #pragma unroll
    for (int i = 0; i < 4; ++i) {
        const int rr = (t >> 4) + i * 16;
        *reinterpret_cast<float4*>(&T[rr][cc]) =
            *reinterpret_cast<const float4*>(&W[(size_t)(wk * 64 + rr) * FOUT + wc * 64 + cc]);
    }
    __syncthreads();
    const int a = t >> 2;
    const int b0 = (t & 3) * 16;
    s16x8 v0, v1;
    #pragma unroll
    for (int e = 0; e < 8; ++e) { v0[e] = f2bf(T[b0 + e][a]); v1[e] = f2bf(T[b0 + 8 + e][a]); }
    short* dst = &WT[(size_t)(wc * 64 + a) * FIN + wk * 64 + b0];
    *reinterpret_cast<s16x8*>(dst) = v0;
    *reinterpret_cast<s16x8*>(dst + 8) = v1;
}

// ---------- Kernel 3 (shared): reg-staged bf16 GEMM (xw + fallback prop) ----------
template<int KLEN, int MODE>
__global__ __launch_bounds__(256, 4) void gemm_kernel(
    const float* __restrict__ A, const short* __restrict__ B,
    const float* __restrict__ d_is,
    short* __restrict__ psT,
    float* __restrict__ P0, float* __restrict__ P1) {
    constexpr int KS = (MODE == 1) ? 2 : 1;
    constexpr int Ksub = KLEN / KS;
    constexpr int NT = Ksub / 32;
    constexpr int LDA = 40;
    __shared__ short As[2][128 * LDA];
    __shared__ short Bs[2][64 * LDA];

    const int tid = threadIdx.x;
    const int nchunk = gridDim.x >> 3;
    const int lin = blockIdx.x;
    const int swz = (lin & 7) * nchunk + (lin >> 3);
    const int col0 = (swz & 7) * 64;
    const int yp = (swz >> 3) & 63;
    const int ks = swz >> 9;
    const int row0 = yp * 128;
    const int kbase = ks * Ksub;

    const int lane = tid & 63;
    const int wv = tid >> 6;
    const int wr = wv >> 1, wc = wv & 1;
    const int l15 = lane & 15;
    const int koff = (lane >> 4) * 8;

    const int ar = tid >> 1, ak = (tid & 1) * 16;
    const float* Abase = A + (size_t)(row0 + ar) * KLEN + kbase + ak;
    const int br = tid >> 2, bk = (tid & 3) * 8;
    const short* Bbase = B + (size_t)(col0 + br) * KLEN + kbase + bk;

    float4 qa0, qa1, qa2, qa3;
    s16x8 qb;
    auto loadG = [&](int k0) {
        const float4* p = reinterpret_cast<const float4*>(Abase + k0);
        qa0 = p[0]; qa1 = p[1]; qa2 = p[2]; qa3 = p[3];
        qb = *reinterpret_cast<const s16x8*>(Bbase + k0);
    };
    auto writeL = [&](int buf) {
        const float a[16] = {qa0.x, qa0.y, qa0.z, qa0.w, qa1.x, qa1.y, qa1.z, qa1.w,
                             qa2.x, qa2.y, qa2.z, qa2.w, qa3.x, qa3.y, qa3.z, qa3.w};
        s16x8 v0, v1;
        #pragma unroll
        for (int e = 0; e < 8; ++e) { v0[e] = f2bf(a[e]); v1[e] = f2bf(a[8 + e]); }
        *reinterpret_cast<s16x8*>(&As[buf][ar * LDA + ak]) = v0;
        *reinterpret_cast<s16x8*>(&As[buf][ar * LDA + ak + 8]) = v1;
        *reinterpret_cast<s16x8*>(&Bs[buf][br * LDA + bk]) = qb;
    };

    f32x4 acc[4][2] = {};
    auto compute = [&](int buf) {
        s16x8 af[4], bfr[2];
        #pragma unroll
        for (int m = 0; m < 4; ++m)
            af[m] = *reinterpret_cast<const s16x8*>(&As[buf][(wr * 64 + m * 16 + l15) * LDA + koff]);
        #pragma unroll
        for (int n = 0; n < 2; ++n)
            bfr[n] = *reinterpret_cast<const s16x8*>(&Bs[buf][(wc * 32 + n * 16 + l15) * LDA + koff]);
        #pragma unroll
        for (int m = 0; m < 4; ++m)
            #pragma unroll
            for (int n = 0; n < 2; ++n)
                acc[m][n] = __builtin_amdgcn_mfma_f32_16x16x32_bf16(af[m], bfr[n], acc[m][n], 0, 0, 0);
    };

    loadG(0);
    writeL(0);
    __syncthreads();
    int cur = 0;
    for (int t = 0; t < NT; ++t) {
        if (t + 1 < NT) loadG((t + 1) * 32);
        compute(cur);
        if (t + 1 < NT) writeL(cur ^ 1);
        __syncthreads();
        cur ^= 1;
    }

    if (MODE == 0) {
        #pragma unroll
        for (int m = 0; m < 4; ++m) {
            const int rbase = row0 + wr * 64 + m * 16 + (lane >> 4) * 4;
            float dr[4];
            #pragma unroll
            for (int j = 0; j < 4; ++j) dr[j] = d_is[rbase + j];
            #pragma unroll
            for (int n = 0; n < 2; ++n) {
                const int col = col0 + wc * 32 + n * 16 + l15;
                u16x4 pk;
                #pragma unroll
                for (int j = 0; j < 4; ++j) pk[j] = (unsigned short)f2bf(dr[j] * acc[m][n][j]);
                *reinterpret_cast<u16x4*>(&psT[(size_t)col * NN + rbase]) = pk;
            }
        }
    } else {
        float* tgt = (ks == 0) ? P0 : P1;
        #pragma unroll
        for (int m = 0; m < 4; ++m) {
            const int rbase = row0 + wr * 64 + m * 16 + (lane >> 4) * 4;
            #pragma unroll
            for (int n = 0; n < 2; ++n) {
                const int col = col0 + wc * 32 + n * 16 + l15;
                f32x4 v = acc[m][n];
                if (ks == 0) {
                    const u16x4 sv = *reinterpret_cast<const u16x4*>(&psT[(size_t)col * NN + rbase]);
                    #pragma unroll
                    for (int j = 0; j < 4; ++j) v[j] += bf2f((short)sv[j]);
                }
                #pragma unroll
                for (int j = 0; j < 4; ++j)
                    tgt[(size_t)(rbase + j) * FOUT + col] = v[j];
            }
        }
    }
}

// ---------- Kernel 4 (path A): 128x128 tile, glds-staged, swizzled, split-K=4 ----------
// A = adjB [8192][8192] bf16, B = psT [512][8192] bf16. Raw f32 partial -> P[ks].
__global__ __launch_bounds__(256, 4) void prop2_kernel(
    const short* __restrict__ adjB, const short* __restrict__ psT,
    float* __restrict__ P0, float* __restrict__ P1,
    float* __restrict__ P2, float* __restrict__ P3) {
    constexpr int Ksub = NN / 4;   // 2048
    constexpr int NT = Ksub / 32;  // 64
    __shared__ short As[2][4096];  // [128][32] bf16, swizzle-permuted content
    __shared__ short Bs[2][4096];

    const int tid = threadIdx.x;
    // chunked XCD swizzle over 1024 blocks: swz = [row-panel(6)][ks(2)][col(2)]
    const int lin = blockIdx.x;
    const int swz = (lin & 7) * 128 + (lin >> 3);
    const int col0 = (swz & 3) * 128;
    const int ks = (swz >> 2) & 3;
    const int row0 = (swz >> 4) * 128;

    const int lane = tid & 63;
    const int wv = tid >> 6;
    const int wr = wv >> 1, wc = wv & 1;   // 2x2 waves, wave tile 64x64
    const int l15 = lane & 15;
    const int kq = lane >> 4;
    const int xorv = (l15 & 12) << 2;      // read-side swizzle: XOR of byte bits 4,5

    // staging: lane's LDS slot -> inverse-swizzled global element
    int arow[2], acoff[2];
    #pragma unroll
    for (int i = 0; i < 2; ++i) {
        const int slot = i * 256 + tid;
        const int P = (slot << 4) ^ (slot & 48);   // swizzled byte offset in 8KB tile
        arow[i] = P >> 6;
        acoff[i] = (P & 63) >> 1;
    }
    const size_t kbase = (size_t)ks * Ksub;
    const short* Ab = adjB + (size_t)row0 * NN + kbase;
    const short* Bb = psT + (size_t)col0 * NN + kbase;

    auto stage = [&](int buf, int k0) {
        #pragma unroll
        for (int i = 0; i < 2; ++i) {
            const short* src = Ab + (size_t)arow[i] * NN + k0 + acoff[i];
            short* dst = &As[buf][(i * 256 + (tid & 192)) * 8];
            __builtin_amdgcn_global_load_lds(
                (const __attribute__((address_space(1))) unsigned int*)src,
                (__attribute__((address_space(3))) unsigned int*)dst, 16, 0, 0);
        }
        #pragma unroll
        for (int i = 0; i < 2; ++i) {
            const short* src = Bb + (size_t)arow[i] * NN + k0 + acoff[i];
            short* dst = &Bs[buf][(i * 256 + (tid & 192)) * 8];
            __builtin_amdgcn_global_load_lds(
                (const __attribute__((address_space(1))) unsigned int*)src,
                (__attribute__((address_space(3))) unsigned int*)dst, 16, 0, 0);
        }
    };

    f32x4 acc[4][4] = {};
    auto compute = [&](int buf) {
        s16x8 af[4], bfr[4];
        #pragma unroll
        for (int m = 0; m < 4; ++m) {
            const int byteoff = ((wr * 64 + m * 16 + l15) * 64 + kq * 16) ^ xorv;
            af[m] = *reinterpret_cast<const s16x8*>(&As[buf][byteoff >> 1]);
        }
        #pragma unroll
        for (int n = 0; n < 4; ++n) {
            const int byteoff = ((wc * 64 + n * 16 + l15) * 64 + kq * 16) ^ xorv;
            bfr[n] = *reinterpret_cast<const s16x8*>(&Bs[buf][byteoff >> 1]);
        }
        #pragma unroll
        for (int m = 0; m < 4; ++m)
            #pragma unroll
            for (int n = 0; n < 4; ++n)
                acc[m][n] = __builtin_amdgcn_mfma_f32_16x16x32_bf16(af[m], bfr[n], acc[m][n], 0, 0, 0);
    };

    stage(0, 0);
    __syncthreads();
    int cur = 0;
    for (int t = 0; t < NT; ++t) {
        if (t + 1 < NT) stage(cur ^ 1, (t + 1) * 32);
        compute(cur);
        __syncthreads();
        cur ^= 1;
    }

    float* Pt = (ks == 0) ? P0 : (ks == 1) ? P1 : (ks == 2) ? P2 : P3;
    #pragma unroll
    for (int m = 0; m < 4; ++m) {
        const int rbase = row0 + wr * 64 + m * 16 + kq * 4;
        #pragma unroll
        for (int n = 0; n < 4; ++n) {
            const int col = col0 + wc * 64 + n * 16 + l15;
            #pragma unroll
            for (int j = 0; j < 4; ++j)
                Pt[(size_t)(rbase + j) * FOUT + col] = acc[m][n][j];
        }
    }
}

// ---------- Kernel 5 (path A): out = relu(d*(P0+P1+P2+P3 + psT^T) + b) ----------
__global__ __launch_bounds__(256) void ep4_kernel(
    const float* __restrict__ P0, const float* __restrict__ P1,
    const float* __restrict__ P2, float* __restrict__ out,
    const short* __restrict__ psT, const float* __restrict__ d_is,
    const float* __restrict__ bias) {
    const int col0 = blockIdx.x * 128;
    const int row0 = blockIdx.y * 32;
    const int t = threadIdx.x;
    const int c = col0 + (t & 31) * 4;
    const float4 bb = *reinterpret_cast<const float4*>(&bias[c]);
    #pragma unroll
    for (int it = 0; it < 4; ++it) {
        const int r = row0 + (t >> 5) + it * 8;
        const size_t idx = (size_t)r * FOUT + c;
        const float4 a = *reinterpret_cast<const float4*>(&P0[idx]);
        const float4 b4 = *reinterpret_cast<const float4*>(&P1[idx]);
        const float4 c4 = *reinterpret_cast<const float4*>(&P2[idx]);
        const float4 d4 = *reinterpret_cast<const float4*>(&out[idx]);
        const float dr = d_is[r];
        float s[4];
        #pragma unroll
        for (int j = 0; j < 4; ++j) s[j] = bf2f(psT[(size_t)(c + j) * NN + r]);
        float4 o;
        o.x = fmaxf(dr * (((a.x + b4.x) + (c4.x + d4.x)) + s[0]) + bb.x, 0.f);
        o.y = fmaxf(dr * (((a.y + b4.y) + (c4.y + d4.y)) + s[1]) + bb.y, 0.f);
        o.z = fmaxf(dr * (((a.z + b4.z) + (c4.z + d4.z)) + s[2]) + bb.z, 0.f);
        o.w = fmaxf(dr * (((a.w + b4.w) + (c4.w + d4.w)) + s[3]) + bb.w, 0.f);
        *reinterpret_cast<float4*>(&out[idx]) = o;
    }
}

// ---------- Kernel 6 (path B fallback): out = relu(d*(P0+P1) + b) ----------
__global__ __launch_bounds__(256) void ep_kernel(const float* __restrict__ P0,
                                                 float* __restrict__ out,
                                                 const float* __restrict__ d_is,
                                                 const float* __restrict__ bias) {
    const size_t idx = ((size_t)blockIdx.x * 256 + threadIdx.x) * 4;
    const int row = (int)(idx >> 9);
    const int col = (int)(idx & 511);
    const float4 p0 = *reinterpret_cast<const float4*>(&P0[idx]);
    const float4 p1 = *reinterpret_cast<const float4*>(&out[idx]);
    const float4 bb = *reinterpret_cast<const float4*>(&bias[col]);
    const float dr = d_is[row];
    float4 o;
    o.x = fmaxf(dr * (p0.x + p1.x) + bb.x, 0.f);
    o.y = fmaxf(dr * (p0.y + p1.y) + bb.y, 0.f);
    o.z = fmaxf(dr * (p0.z + p1.z) + bb.z, 0.f);
    o.w = fmaxf(dr * (p0.w + p1.w) + bb.w, 0.f);
    *reinterpret_cast<float4*>(&out[idx]) = o;
}

extern "C" void kernel_launch(void* const* d_in, const int* in_sizes, int n_in,
                              void* d_out, int out_size, void* d_ws, size_t ws_size,
                              hipStream_t stream) {
    const float* x   = (const float*)d_in[0];
    const float* adj = (const float*)d_in[1];
    const float* W   = (const float*)d_in[2];
    const float* b   = (const float*)d_in[3];
    float* out = (float*)d_out;

    // Path A layout: psT | WT | P0 | P1 | P2 | dis | adjB
    const size_t NEED = (size_t)FOUT * NN * 2 + (size_t)FOUT * FIN * 2
                      + 3ull * NN * FOUT * 4 + NN * 4 + (size_t)NN * NN * 2;

    if (ws_size >= NEED) {
        short* psT = (short*)d_ws;
        short* WT  = psT + (size_t)FOUT * NN;
        float* P0  = (float*)(WT + (size_t)FOUT * FIN);
        float* P1  = P0 + (size_t)NN * FOUT;
        float* P2  = P1 + (size_t)NN * FOUT;
        float* dis = P2 + (size_t)NN * FOUT;
        short* adjB = (short*)(dis + NN);

        hipLaunchKernelGGL(rowsum_cvt_kernel, dim3(NN), dim3(256), 0, stream, adj, adjB, dis);
        hipLaunchKernelGGL(wt_kernel, dim3(8, 16), dim3(256), 0, stream, W, WT);
        hipLaunchKernelGGL((gemm_kernel<FIN, 0>), dim3(512), dim3(256), 0, stream,
                           x, WT, dis, psT, nullptr, nullptr);
        hipLaunchKernelGGL(prop2_kernel, dim3(1024), dim3(256), 0, stream,
                           adjB, psT, P0, P1, P2, out);
        hipLaunchKernelGGL(ep4_kernel, dim3(4, 256), dim3(256), 0, stream,
                           P0, P1, P2, out, psT, dis, b);
    } else {
        short* psT = (short*)d_ws;
        short* WT  = psT + (size_t)FOUT * NN;
        float* P0  = (float*)(WT + (size_t)FOUT * FIN);
        float* dis = P0 + (size_t)NN * FOUT;

        hipLaunchKernelGGL(rowsum_kernel, dim3(NN), dim3(256), 0, stream, adj, dis);
        hipLaunchKernelGGL(wt_kernel, dim3(8, 16), dim3(256), 0, stream, W, WT);
        hipLaunchKernelGGL((gemm_kernel<FIN, 0>), dim3(512), dim3(256), 0, stream,
                           x, WT, dis, psT, nullptr, nullptr);
        hipLaunchKernelGGL((gemm_kernel<NN, 1>), dim3(1024), dim3(256), 0, stream,
                           adj, psT, dis, psT, P0, out);
        hipLaunchKernelGGL(ep_kernel, dim3(NN * FOUT / 1024), dim3(256), 0, stream,
                           P0, out, dis, b);
    }
}

// Round 5
// 225.288 us; speedup vs baseline: 5.2715x; 1.0835x over previous
//
#include <hip/hip_runtime.h>
#include <stdint.h>

#define NN 8192
#define FIN 1024
#define FOUT 512

typedef __attribute__((ext_vector_type(4))) float f32x4;
typedef __attribute__((ext_vector_type(8))) short s16x8;
typedef __attribute__((ext_vector_type(4))) unsigned short u16x4;

__device__ __forceinline__ short f2bf(float f) {
    return __builtin_bit_cast(short, static_cast<__bf16>(f));
}
__device__ __forceinline__ float bf2f(short s) {
    return (float)__builtin_bit_cast(__bf16, s);
}

// ---------- Kernel 1: d_is = 1/sqrt(rowsum+1)  AND  adjB = bf16(adj) ----------
__global__ __launch_bounds__(256) void rowsum_cvt_kernel(const float* __restrict__ adj,
                                                         short* __restrict__ adjB,
                                                         float* __restrict__ d_is) {
    const int row = blockIdx.x;
    const float4* a = reinterpret_cast<const float4*>(adj + (size_t)row * NN);
    u16x4* ob = reinterpret_cast<u16x4*>(adjB + (size_t)row * NN);
    float s = 0.f;
    #pragma unroll 2
    for (int j = threadIdx.x; j < NN / 4; j += 256) {
        float4 v = a[j];
        s += (v.x + v.y) + (v.z + v.w);
        u16x4 p;
        p[0] = (unsigned short)f2bf(v.x); p[1] = (unsigned short)f2bf(v.y);
        p[2] = (unsigned short)f2bf(v.z); p[3] = (unsigned short)f2bf(v.w);
        ob[j] = p;
    }
    #pragma unroll
    for (int off = 32; off > 0; off >>= 1) s += __shfl_down(s, off, 64);
    __shared__ float red[4];
    if ((threadIdx.x & 63) == 0) red[threadIdx.x >> 6] = s;
    __syncthreads();
    if (threadIdx.x == 0) {
        const float d = red[0] + red[1] + red[2] + red[3] + 1.0f;
        d_is[row] = 1.0f / sqrtf(d);
    }
}

// ---------- Kernel 1B (fallback): rowsum only ----------
__global__ __launch_bounds__(256) void rowsum_kernel(const float* __restrict__ adj,
                                                     float* __restrict__ d_is) {
    const int row = blockIdx.x;
    const float4* a = reinterpret_cast<const float4*>(adj + (size_t)row * NN);
    float s = 0.f;
    #pragma unroll 4
    for (int j = threadIdx.x; j < NN / 4; j += 256) {
        float4 v = a[j];
        s += (v.x + v.y) + (v.z + v.w);
    }
    #pragma unroll
    for (int off = 32; off > 0; off >>= 1) s += __shfl_down(s, off, 64);
    __shared__ float red[4];
    if ((threadIdx.x & 63) == 0) red[threadIdx.x >> 6] = s;
    __syncthreads();
    if (threadIdx.x == 0) {
        const float d = red[0] + red[1] + red[2] + red[3] + 1.0f;
        d_is[row] = 1.0f / sqrtf(d);
    }
}

// ---------- Kernel 2: xB = bf16(x) ----------
__global__ __launch_bounds__(256) void cvt_x_kernel(const float* __restrict__ x,
                                                    short* __restrict__ xB) {
    const size_t i = ((size_t)blockIdx.x * 256 + threadIdx.x) * 8;
    const float4 v0 = *reinterpret_cast<const float4*>(&x[i]);
    const float4 v1 = *reinterpret_cast<const float4*>(&x[i + 4]);
    s16x8 o;
    o[0] = f2bf(v0.x); o[1] = f2bf(v0.y); o[2] = f2bf(v0.z); o[3] = f2bf(v0.w);
    o[4] = f2bf(v1.x); o[5] = f2bf(v1.y); o[6] = f2bf(v1.z); o[7] = f2bf(v1.w);
    *reinterpret_cast<s16x8*>(&xB[i]) = o;
}

// ---------- Kernel 3: WT[c][k] = bf16(W[k][c]) ----------
__global__ __launch_bounds__(256) void wt_kernel(const float* __restrict__ W,
                                                 short* __restrict__ WT) {
    __shared__ float T[64][68];
    const int wc = blockIdx.x;
    const int wk = blockIdx.y;
    const int t = threadIdx.x;
    const int cc = (t & 15) * 4;
    #pragma unroll
    for (int i = 0; i < 4; ++i) {
        const int rr = (t >> 4) + i * 16;
        *reinterpret_cast<float4*>(&T[rr][cc]) =
            *reinterpret_cast<const float4*>(&W[(size_t)(wk * 64 + rr) * FOUT + wc * 64 + cc]);
    }
    __syncthreads();
    const int a = t >> 2;
    const int b0 = (t & 3) * 16;
    s16x8 v0, v1;
    #pragma unroll
    for (int e = 0; e < 8; ++e) { v0[e] = f2bf(T[b0 + e][a]); v1[e] = f2bf(T[b0 + 8 + e][a]); }
    short* dst = &WT[(size_t)(wc * 64 + a) * FIN + wk * 64 + b0];
    *reinterpret_cast<s16x8*>(dst) = v0;
    *reinterpret_cast<s16x8*>(dst + 8) = v1;
}

// ---------- Kernel 4: xwg — glds-staged bf16 GEMM, 128x64 tile, BK=32 ----------
// A = xB [8192][1024], B = WT [512][1024]. psT[c][r] = bf16(d_is[r] * acc).
__global__ __launch_bounds__(256, 4) void xwg_kernel(const short* __restrict__ xB,
                                                     const short* __restrict__ WT,
                                                     const float* __restrict__ d_is,
                                                     short* __restrict__ psT) {
    constexpr int NT = FIN / 32;  // 32
    __shared__ short As[2][4096];  // [128][32] swizzled
    __shared__ short Bs[2][2048];  // [64][32]  swizzled

    const int tid = threadIdx.x;
    // chunked XCD swizzle over 512 blocks: 8 row-panels x 8 cols per XCD
    const int lin = blockIdx.x;
    const int swz = (lin & 7) * 64 + (lin >> 3);
    const int col0 = (swz & 7) * 64;
    const int row0 = (swz >> 3) * 128;

    const int lane = tid & 63;
    const int wv = tid >> 6;
    const int wr = wv >> 1, wc = wv & 1;  // wave tile 64x32
    const int l15 = lane & 15;
    const int kq = lane >> 4;
    const int xorv = (l15 & 12) << 2;

    int arow[2], acoff[2];
    #pragma unroll
    for (int i = 0; i < 2; ++i) {
        const int slot = i * 256 + tid;
        const int P = (slot << 4) ^ (slot & 48);
        arow[i] = P >> 6;
        acoff[i] = (P & 63) >> 1;
    }
    const short* Ab = xB + (size_t)row0 * FIN;
    const short* Bb = WT + (size_t)col0 * FIN;

    auto stage = [&](int buf, int k0) {
        #pragma unroll
        for (int i = 0; i < 2; ++i) {
            const short* src = Ab + (size_t)arow[i] * FIN + k0 + acoff[i];
            short* dst = &As[buf][(i * 256 + (tid & 192)) * 8];
            __builtin_amdgcn_global_load_lds(
                (const __attribute__((address_space(1))) unsigned int*)src,
                (__attribute__((address_space(3))) unsigned int*)dst, 16, 0, 0);
        }
        {
            const short* src = Bb + (size_t)arow[0] * FIN + k0 + acoff[0];
            short* dst = &Bs[buf][(tid & 192) * 8];
            __builtin_amdgcn_global_load_lds(
                (const __attribute__((address_space(1))) unsigned int*)src,
                (__attribute__((address_space(3))) unsigned int*)dst, 16, 0, 0);
        }
    };

    f32x4 acc[4][2] = {};
    auto compute = [&](int buf) {
        s16x8 af[4], bfr[2];
        #pragma unroll
        for (int m = 0; m < 4; ++m) {
            const int byteoff = ((wr * 64 + m * 16 + l15) * 64 + kq * 16) ^ xorv;
            af[m] = *reinterpret_cast<const s16x8*>(&As[buf][byteoff >> 1]);
        }
        #pragma unroll
        for (int n = 0; n < 2; ++n) {
            const int byteoff = ((wc * 32 + n * 16 + l15) * 64 + kq * 16) ^ xorv;
            bfr[n] = *reinterpret_cast<const s16x8*>(&Bs[buf][byteoff >> 1]);
        }
        #pragma unroll
        for (int m = 0; m < 4; ++m)
            #pragma unroll
            for (int n = 0; n < 2; ++n)
                acc[m][n] = __builtin_amdgcn_mfma_f32_16x16x32_bf16(af[m], bfr[n], acc[m][n], 0, 0, 0);
    };

    stage(0, 0);
    __syncthreads();
    int cur = 0;
    for (int t = 0; t < NT; ++t) {
        if (t + 1 < NT) stage(cur ^ 1, (t + 1) * 32);
        compute(cur);
        __syncthreads();
        cur ^= 1;
    }

    #pragma unroll
    for (int m = 0; m < 4; ++m) {
        const int rbase = row0 + wr * 64 + m * 16 + kq * 4;
        float dr[4];
        #pragma unroll
        for (int j = 0; j < 4; ++j) dr[j] = d_is[rbase + j];
        #pragma unroll
        for (int n = 0; n < 2; ++n) {
            const int col = col0 + wc * 32 + n * 16 + l15;
            u16x4 pk;
            #pragma unroll
            for (int j = 0; j < 4; ++j) pk[j] = (unsigned short)f2bf(dr[j] * acc[m][n][j]);
            *reinterpret_cast<u16x4*>(&psT[(size_t)col * NN + rbase]) = pk;
        }
    }
}

// ---------- Kernel 5: prop2 — 128x128 glds-staged, split-K=4, bf16 partials ----------
__global__ __launch_bounds__(256, 4) void prop2_kernel(
    const short* __restrict__ adjB, const short* __restrict__ psT,
    short* __restrict__ Pb0, short* __restrict__ Pb1,
    short* __restrict__ Pb2, float* __restrict__ Pf) {
    constexpr int Ksub = NN / 4;   // 2048
    constexpr int NT = Ksub / 32;  // 64
    __shared__ short As[2][4096];
    __shared__ short Bs[2][4096];

    const int tid = threadIdx.x;
    const int lin = blockIdx.x;
    const int swz = (lin & 7) * 128 + (lin >> 3);
    const int col0 = (swz & 3) * 128;
    const int ks = (swz >> 2) & 3;
    const int row0 = (swz >> 4) * 128;

    const int lane = tid & 63;
    const int wv = tid >> 6;
    const int wr = wv >> 1, wc = wv & 1;   // wave tile 64x64
    const int l15 = lane & 15;
    const int kq = lane >> 4;
    const int xorv = (l15 & 12) << 2;

    int arow[2], acoff[2];
    #pragma unroll
    for (int i = 0; i < 2; ++i) {
        const int slot = i * 256 + tid;
        const int P = (slot << 4) ^ (slot & 48);
        arow[i] = P >> 6;
        acoff[i] = (P & 63) >> 1;
    }
    const size_t kbase = (size_t)ks * Ksub;
    const short* Ab = adjB + (size_t)row0 * NN + kbase;
    const short* Bb = psT + (size_t)col0 * NN + kbase;

    auto stage = [&](int buf, int k0) {
        #pragma unroll
        for (int i = 0; i < 2; ++i) {
            const short* src = Ab + (size_t)arow[i] * NN + k0 + acoff[i];
            short* dst = &As[buf][(i * 256 + (tid & 192)) * 8];
            __builtin_amdgcn_global_load_lds(
                (const __attribute__((address_space(1))) unsigned int*)src,
                (__attribute__((address_space(3))) unsigned int*)dst, 16, 0, 0);
        }
        #pragma unroll
        for (int i = 0; i < 2; ++i) {
            const short* src = Bb + (size_t)arow[i] * NN + k0 + acoff[i];
            short* dst = &Bs[buf][(i * 256 + (tid & 192)) * 8];
            __builtin_amdgcn_global_load_lds(
                (const __attribute__((address_space(1))) unsigned int*)src,
                (__attribute__((address_space(3))) unsigned int*)dst, 16, 0, 0);
        }
    };

    f32x4 acc[4][4] = {};
    auto compute = [&](int buf) {
        s16x8 af[4], bfr[4];
        #pragma unroll
        for (int m = 0; m < 4; ++m) {
            const int byteoff = ((wr * 64 + m * 16 + l15) * 64 + kq * 16) ^ xorv;
            af[m] = *reinterpret_cast<const s16x8*>(&As[buf][byteoff >> 1]);
        }
        #pragma unroll
        for (int n = 0; n < 4; ++n) {
            const int byteoff = ((wc * 64 + n * 16 + l15) * 64 + kq * 16) ^ xorv;
            bfr[n] = *reinterpret_cast<const s16x8*>(&Bs[buf][byteoff >> 1]);
        }
        #pragma unroll
        for (int m = 0; m < 4; ++m)
            #pragma unroll
            for (int n = 0; n < 4; ++n)
                acc[m][n] = __builtin_amdgcn_mfma_f32_16x16x32_bf16(af[m], bfr[n], acc[m][n], 0, 0, 0);
    };

    stage(0, 0);
    __syncthreads();
    int cur = 0;
    for (int t = 0; t < NT; ++t) {
        if (t + 1 < NT) stage(cur ^ 1, (t + 1) * 32);
        compute(cur);
        __syncthreads();
        cur ^= 1;
    }

    if (ks == 3) {
        #pragma unroll
        for (int m = 0; m < 4; ++m) {
            const int rbase = row0 + wr * 64 + m * 16 + kq * 4;
            #pragma unroll
            for (int n = 0; n < 4; ++n) {
                const int col = col0 + wc * 64 + n * 16 + l15;
                #pragma unroll
                for (int j = 0; j < 4; ++j)
                    Pf[(size_t)(rbase + j) * FOUT + col] = acc[m][n][j];
            }
        }
    } else {
        short* Pt = (ks == 0) ? Pb0 : (ks == 1) ? Pb1 : Pb2;
        #pragma unroll
        for (int m = 0; m < 4; ++m) {
            const int rbase = row0 + wr * 64 + m * 16 + kq * 4;
            #pragma unroll
            for (int n = 0; n < 4; ++n) {
                const int col = col0 + wc * 64 + n * 16 + l15;
                #pragma unroll
                for (int j = 0; j < 4; ++j)
                    Pt[(size_t)(rbase + j) * FOUT + col] = f2bf(acc[m][n][j]);
            }
        }
    }
}

// ---------- Kernel 6: out = relu(d*(Pb0+Pb1+Pb2+Pf + psT^T) + b) ----------
__global__ __launch_bounds__(256) void ep4_kernel(
    const short* __restrict__ Pb0, const short* __restrict__ Pb1,
    const short* __restrict__ Pb2, float* __restrict__ out,
    const short* __restrict__ psT, const float* __restrict__ d_is,
    const float* __restrict__ bias) {
    const int col0 = blockIdx.x * 128;
    const int row0 = blockIdx.y * 32;
    const int t = threadIdx.x;
    const int c = col0 + (t & 31) * 4;
    const float4 bb = *reinterpret_cast<const float4*>(&bias[c]);
    #pragma unroll
    for (int it = 0; it < 4; ++it) {
        const int r = row0 + (t >> 5) + it * 8;
        const size_t idx = (size_t)r * FOUT + c;
        const u16x4 a = *reinterpret_cast<const u16x4*>(&Pb0[idx]);
        const u16x4 b4 = *reinterpret_cast<const u16x4*>(&Pb1[idx]);
        const u16x4 c4 = *reinterpret_cast<const u16x4*>(&Pb2[idx]);
        const float4 d4 = *reinterpret_cast<const float4*>(&out[idx]);
        const float dr = d_is[r];
        float s[4], o4[4];
        #pragma unroll
        for (int j = 0; j < 4; ++j) s[j] = bf2f(psT[(size_t)(c + j) * NN + r]);
        const float dd[4] = {d4.x, d4.y, d4.z, d4.w};
        const float bbv[4] = {bb.x, bb.y, bb.z, bb.w};
        #pragma unroll
        for (int j = 0; j < 4; ++j) {
            const float sum = ((bf2f((short)a[j]) + bf2f((short)b4[j])) +
                               (bf2f((short)c4[j]) + dd[j])) + s[j];
            o4[j] = fmaxf(dr * sum + bbv[j], 0.f);
        }
        float4 o = {o4[0], o4[1], o4[2], o4[3]};
        *reinterpret_cast<float4*>(&out[idx]) = o;
    }
}

// ---------- Fallback kernels (small-ws path, unchanged from prior round) ----------
template<int KLEN, int MODE>
__global__ __launch_bounds__(256, 4) void gemm_kernel(
    const float* __restrict__ A, const short* __restrict__ B,
    const float* __restrict__ d_is,
    short* __restrict__ psT,
    float* __restrict__ P0, float* __restrict__ P1) {
    constexpr int KS = (MODE == 1) ? 2 : 1;
    constexpr int Ksub = KLEN / KS;
    constexpr int NT = Ksub / 32;
    constexpr int LDA = 40;
    __shared__ short As[2][128 * LDA];
    __shared__ short Bs[2][64 * LDA];

    const int tid = threadIdx.x;
    const int nchunk = gridDim.x >> 3;
    const int lin = blockIdx.x;
    const int swz = (lin & 7) * nchunk + (lin >> 3);
    const int col0 = (swz & 7) * 64;
    const int yp = (swz >> 3) & 63;
    const int ks = swz >> 9;
    const int row0 = yp * 128;
    const int kbase = ks * Ksub;

    const int lane = tid & 63;
    const int wv = tid >> 6;
    const int wr = wv >> 1, wc = wv & 1;
    const int l15 = lane & 15;
    const int koff = (lane >> 4) * 8;

    const int ar = tid >> 1, ak = (tid & 1) * 16;
    const float* Abase = A + (size_t)(row0 + ar) * KLEN + kbase + ak;
    const int br = tid >> 2, bk = (tid & 3) * 8;
    const short* Bbase = B + (size_t)(col0 + br) * KLEN + kbase + bk;

    float4 qa0, qa1, qa2, qa3;
    s16x8 qb;
    auto loadG = [&](int k0) {
        const float4* p = reinterpret_cast<const float4*>(Abase + k0);
        qa0 = p[0]; qa1 = p[1]; qa2 = p[2]; qa3 = p[3];
        qb = *reinterpret_cast<const s16x8*>(Bbase + k0);
    };
    auto writeL = [&](int buf) {
        const float a[16] = {qa0.x, qa0.y, qa0.z, qa0.w, qa1.x, qa1.y, qa1.z, qa1.w,
                             qa2.x, qa2.y, qa2.z, qa2.w, qa3.x, qa3.y, qa3.z, qa3.w};
        s16x8 v0, v1;
        #pragma unroll
        for (int e = 0; e < 8; ++e) { v0[e] = f2bf(a[e]); v1[e] = f2bf(a[8 + e]); }
        *reinterpret_cast<s16x8*>(&As[buf][ar * LDA + ak]) = v0;
        *reinterpret_cast<s16x8*>(&As[buf][ar * LDA + ak + 8]) = v1;
        *reinterpret_cast<s16x8*>(&Bs[buf][br * LDA + bk]) = qb;
    };

    f32x4 acc[4][2] = {};
    auto compute = [&](int buf) {
        s16x8 af[4], bfr[2];
        #pragma unroll
        for (int m = 0; m < 4; ++m)
            af[m] = *reinterpret_cast<const s16x8*>(&As[buf][(wr * 64 + m * 16 + l15) * LDA + koff]);
        #pragma unroll
        for (int n = 0; n < 2; ++n)
            bfr[n] = *reinterpret_cast<const s16x8*>(&Bs[buf][(wc * 32 + n * 16 + l15) * LDA + koff]);
        #pragma unroll
        for (int m = 0; m < 4; ++m)
            #pragma unroll
            for (int n = 0; n < 2; ++n)
                acc[m][n] = __builtin_amdgcn_mfma_f32_16x16x32_bf16(af[m], bfr[n], acc[m][n], 0, 0, 0);
    };

    loadG(0);
    writeL(0);
    __syncthreads();
    int cur = 0;
    for (int t = 0; t < NT; ++t) {
        if (t + 1 < NT) loadG((t + 1) * 32);
        compute(cur);
        if (t + 1 < NT) writeL(cur ^ 1);
        __syncthreads();
        cur ^= 1;
    }

    if (MODE == 0) {
        #pragma unroll
        for (int m = 0; m < 4; ++m) {
            const int rbase = row0 + wr * 64 + m * 16 + (lane >> 4) * 4;
            float dr[4];
            #pragma unroll
            for (int j = 0; j < 4; ++j) dr[j] = d_is[rbase + j];
            #pragma unroll
            for (int n = 0; n < 2; ++n) {
                const int col = col0 + wc * 32 + n * 16 + l15;
                u16x4 pk;
                #pragma unroll
                for (int j = 0; j < 4; ++j) pk[j] = (unsigned short)f2bf(dr[j] * acc[m][n][j]);
                *reinterpret_cast<u16x4*>(&psT[(size_t)col * NN + rbase]) = pk;
            }
        }
    } else {
        float* tgt = (ks == 0) ? P0 : P1;
        #pragma unroll
        for (int m = 0; m < 4; ++m) {
            const int rbase = row0 + wr * 64 + m * 16 + (lane >> 4) * 4;
            #pragma unroll
            for (int n = 0; n < 2; ++n) {
                const int col = col0 + wc * 32 + n * 16 + l15;
                f32x4 v = acc[m][n];
                if (ks == 0) {
                    const u16x4 sv = *reinterpret_cast<const u16x4*>(&psT[(size_t)col * NN + rbase]);
                    #pragma unroll
                    for (int j = 0; j < 4; ++j) v[j] += bf2f((short)sv[j]);
                }
                #pragma unroll
                for (int j = 0; j < 4; ++j)
                    tgt[(size_t)(rbase + j) * FOUT + col] = v[j];
            }
        }
    }
}

__global__ __launch_bounds__(256) void ep_kernel(const float* __restrict__ P0,
                                                 float* __restrict__ out,
                                                 const float* __restrict__ d_is,
                                                 const float* __restrict__ bias) {
    const size_t idx = ((size_t)blockIdx.x * 256 + threadIdx.x) * 4;
    const int row = (int)(idx >> 9);
    const int col = (int)(idx & 511);
    const float4 p0 = *reinterpret_cast<const float4*>(&P0[idx]);
    const float4 p1 = *reinterpret_cast<const float4*>(&out[idx]);
    const float4 bb = *reinterpret_cast<const float4*>(&bias[col]);
    const float dr = d_is[row];
    float4 o;
    o.x = fmaxf(dr * (p0.x + p1.x) + bb.x, 0.f);
    o.y = fmaxf(dr * (p0.y + p1.y) + bb.y, 0.f);
    o.z = fmaxf(dr * (p0.z + p1.z) + bb.z, 0.f);
    o.w = fmaxf(dr * (p0.w + p1.w) + bb.w, 0.f);
    *reinterpret_cast<float4*>(&out[idx]) = o;
}

extern "C" void kernel_launch(void* const* d_in, const int* in_sizes, int n_in,
                              void* d_out, int out_size, void* d_ws, size_t ws_size,
                              hipStream_t stream) {
    const float* x   = (const float*)d_in[0];
    const float* adj = (const float*)d_in[1];
    const float* W   = (const float*)d_in[2];
    const float* b   = (const float*)d_in[3];
    float* out = (float*)d_out;

    // Path A layout: psT | WT | xB | Pb0 | Pb1 | Pb2 | dis | adjB
    const size_t NEED = (size_t)FOUT * NN * 2 + (size_t)FOUT * FIN * 2
                      + (size_t)NN * FIN * 2 + 3ull * NN * FOUT * 2
                      + NN * 4 + (size_t)NN * NN * 2;

    if (ws_size >= NEED) {
        short* psT = (short*)d_ws;
        short* WT  = psT + (size_t)FOUT * NN;
        short* xB  = WT + (size_t)FOUT * FIN;
        short* Pb0 = xB + (size_t)NN * FIN;
        short* Pb1 = Pb0 + (size_t)NN * FOUT;
        short* Pb2 = Pb1 + (size_t)NN * FOUT;
        float* dis = (float*)(Pb2 + (size_t)NN * FOUT);
        short* adjB = (short*)(dis + NN);

        hipLaunchKernelGGL(rowsum_cvt_kernel, dim3(NN), dim3(256), 0, stream, adj, adjB, dis);
        hipLaunchKernelGGL(cvt_x_kernel, dim3(NN * FIN / 2048), dim3(256), 0, stream, x, xB);
        hipLaunchKernelGGL(wt_kernel, dim3(8, 16), dim3(256), 0, stream, W, WT);
        hipLaunchKernelGGL(xwg_kernel, dim3(512), dim3(256), 0, stream, xB, WT, dis, psT);
        hipLaunchKernelGGL(prop2_kernel, dim3(1024), dim3(256), 0, stream,
                           adjB, psT, Pb0, Pb1, Pb2, out);
        hipLaunchKernelGGL(ep4_kernel, dim3(4, 256), dim3(256), 0, stream,
                           Pb0, Pb1, Pb2, out, psT, dis, b);
    } else {
        short* psT = (short*)d_ws;
        short* WT  = psT + (size_t)FOUT * NN;
        float* P0  = (float*)(WT + (size_t)FOUT * FIN);
        float* dis = P0 + (size_t)NN * FOUT;

        hipLaunchKernelGGL(rowsum_kernel, dim3(NN), dim3(256), 0, stream, adj, dis);
        hipLaunchKernelGGL(wt_kernel, dim3(8, 16), dim3(256), 0, stream, W, WT);
        hipLaunchKernelGGL((gemm_kernel<FIN, 0>), dim3(512), dim3(256), 0, stream,
                           x, WT, dis, psT, nullptr, nullptr);
        hipLaunchKernelGGL((gemm_kernel<NN, 1>), dim3(1024), dim3(256), 0, stream,
                           adj, psT, dis, psT, P0, out);
        hipLaunchKernelGGL(ep_kernel, dim3(NN * FOUT / 1024), dim3(256), 0, stream,
                           P0, out, dis, b);
    }
}

// Round 6
// 218.102 us; speedup vs baseline: 5.4452x; 1.0330x over previous
//
#include <hip/hip_runtime.h>
#include <stdint.h>

#define NN 8192
#define FIN 1024
#define FOUT 512

typedef __attribute__((ext_vector_type(4))) float f32x4;
typedef __attribute__((ext_vector_type(8))) short s16x8;
typedef __attribute__((ext_vector_type(4))) unsigned short u16x4;

__device__ __forceinline__ short f2bf(float f) {
    return __builtin_bit_cast(short, static_cast<__bf16>(f));
}
__device__ __forceinline__ float bf2f(short s) {
    return (float)__builtin_bit_cast(__bf16, s);
}

// ---------- Kernel 1: d_is = 1/sqrt(rowsum+1)  AND  adjB = bf16(adj) ----------
__global__ __launch_bounds__(256) void rowsum_cvt_kernel(const float* __restrict__ adj,
                                                         short* __restrict__ adjB,
                                                         float* __restrict__ d_is) {
    const int row = blockIdx.x;
    const float4* a = reinterpret_cast<const float4*>(adj + (size_t)row * NN);
    u16x4* ob = reinterpret_cast<u16x4*>(adjB + (size_t)row * NN);
    float s = 0.f;
    #pragma unroll 2
    for (int j = threadIdx.x; j < NN / 4; j += 256) {
        float4 v = a[j];
        s += (v.x + v.y) + (v.z + v.w);
        u16x4 p;
        p[0] = (unsigned short)f2bf(v.x); p[1] = (unsigned short)f2bf(v.y);
        p[2] = (unsigned short)f2bf(v.z); p[3] = (unsigned short)f2bf(v.w);
        ob[j] = p;
    }
    #pragma unroll
    for (int off = 32; off > 0; off >>= 1) s += __shfl_down(s, off, 64);
    __shared__ float red[4];
    if ((threadIdx.x & 63) == 0) red[threadIdx.x >> 6] = s;
    __syncthreads();
    if (threadIdx.x == 0) {
        const float d = red[0] + red[1] + red[2] + red[3] + 1.0f;
        d_is[row] = 1.0f / sqrtf(d);
    }
}

// ---------- Kernel 1B (fallback): rowsum only ----------
__global__ __launch_bounds__(256) void rowsum_kernel(const float* __restrict__ adj,
                                                     float* __restrict__ d_is) {
    const int row = blockIdx.x;
    const float4* a = reinterpret_cast<const float4*>(adj + (size_t)row * NN);
    float s = 0.f;
    #pragma unroll 4
    for (int j = threadIdx.x; j < NN / 4; j += 256) {
        float4 v = a[j];
        s += (v.x + v.y) + (v.z + v.w);
    }
    #pragma unroll
    for (int off = 32; off > 0; off >>= 1) s += __shfl_down(s, off, 64);
    __shared__ float red[4];
    if ((threadIdx.x & 63) == 0) red[threadIdx.x >> 6] = s;
    __syncthreads();
    if (threadIdx.x == 0) {
        const float d = red[0] + red[1] + red[2] + red[3] + 1.0f;
        d_is[row] = 1.0f / sqrtf(d);
    }
}

// ---------- Kernel 2: xB = bf16(x) ----------
__global__ __launch_bounds__(256) void cvt_x_kernel(const float* __restrict__ x,
                                                    short* __restrict__ xB) {
    const size_t i = ((size_t)blockIdx.x * 256 + threadIdx.x) * 8;
    const float4 v0 = *reinterpret_cast<const float4*>(&x[i]);
    const float4 v1 = *reinterpret_cast<const float4*>(&x[i + 4]);
    s16x8 o;
    o[0] = f2bf(v0.x); o[1] = f2bf(v0.y); o[2] = f2bf(v0.z); o[3] = f2bf(v0.w);
    o[4] = f2bf(v1.x); o[5] = f2bf(v1.y); o[6] = f2bf(v1.z); o[7] = f2bf(v1.w);
    *reinterpret_cast<s16x8*>(&xB[i]) = o;
}

// ---------- Kernel 3: WT[c][k] = bf16(W[k][c]) ----------
__global__ __launch_bounds__(256) void wt_kernel(const float* __restrict__ W,
                                                 short* __restrict__ WT) {
    __shared__ float T[64][68];
    const int wc = blockIdx.x;
    const int wk = blockIdx.y;
    const int t = threadIdx.x;
    const int cc = (t & 15) * 4;
    #pragma unroll
    for (int i = 0; i < 4; ++i) {
        const int rr = (t >> 4) + i * 16;
        *reinterpret_cast<float4*>(&T[rr][cc]) =
            *reinterpret_cast<const float4*>(&W[(size_t)(wk * 64 + rr) * FOUT + wc * 64 + cc]);
    }
    __syncthreads();
    const int a = t >> 2;
    const int b0 = (t & 3) * 16;
    s16x8 v0, v1;
    #pragma unroll
    for (int e = 0; e < 8; ++e) { v0[e] = f2bf(T[b0 + e][a]); v1[e] = f2bf(T[b0 + 8 + e][a]); }
    short* dst = &WT[(size_t)(wc * 64 + a) * FIN + wk * 64 + b0];
    *reinterpret_cast<s16x8*>(dst) = v0;
    *reinterpret_cast<s16x8*>(dst + 8) = v1;
}

// ---------- Kernel 4: xwg — glds-staged bf16 GEMM, counted-vmcnt pipeline ----------
// A = xB [8192][1024], B = WT [512][1024]. psT[c][r] = bf16(d_is[r] * acc).
__global__ __launch_bounds__(256, 4) void xwg_kernel(const short* __restrict__ xB,
                                                     const short* __restrict__ WT,
                                                     const float* __restrict__ d_is,
                                                     short* __restrict__ psT) {
    constexpr int NT = FIN / 32;  // 32
    __shared__ short As[2][4096];  // [128][32] swizzled
    __shared__ short Bs[2][2048];  // [64][32]  swizzled

    const int tid = threadIdx.x;
    const int lin = blockIdx.x;
    const int swz = (lin & 7) * 64 + (lin >> 3);
    const int col0 = (swz & 7) * 64;
    const int row0 = (swz >> 3) * 128;

    const int lane = tid & 63;
    const int wv = tid >> 6;
    const int wr = wv >> 1, wc = wv & 1;  // wave tile 64x32
    const int l15 = lane & 15;
    const int kq = lane >> 4;
    const int xorv = (l15 & 12) << 2;

    int arow[2], acoff[2];
    #pragma unroll
    for (int i = 0; i < 2; ++i) {
        const int slot = i * 256 + tid;
        const int P = (slot << 4) ^ (slot & 48);
        arow[i] = P >> 6;
        acoff[i] = (P & 63) >> 1;
    }
    const short* Ab = xB + (size_t)row0 * FIN;
    const short* Bb = WT + (size_t)col0 * FIN;

    auto stage = [&](int buf, int k0) {  // 3 vmem instructions per call
        #pragma unroll
        for (int i = 0; i < 2; ++i) {
            const short* src = Ab + (size_t)arow[i] * FIN + k0 + acoff[i];
            short* dst = &As[buf][(i * 256 + (tid & 192)) * 8];
            __builtin_amdgcn_global_load_lds(
                (const __attribute__((address_space(1))) unsigned int*)src,
                (__attribute__((address_space(3))) unsigned int*)dst, 16, 0, 0);
        }
        {
            const short* src = Bb + (size_t)arow[0] * FIN + k0 + acoff[0];
            short* dst = &Bs[buf][(tid & 192) * 8];
            __builtin_amdgcn_global_load_lds(
                (const __attribute__((address_space(1))) unsigned int*)src,
                (__attribute__((address_space(3))) unsigned int*)dst, 16, 0, 0);
        }
    };

    f32x4 acc[4][2] = {};
    auto compute = [&](int buf) {
        s16x8 af[4], bfr[2];
        #pragma unroll
        for (int m = 0; m < 4; ++m) {
            const int byteoff = ((wr * 64 + m * 16 + l15) * 64 + kq * 16) ^ xorv;
            af[m] = *reinterpret_cast<const s16x8*>(&As[buf][byteoff >> 1]);
        }
        #pragma unroll
        for (int n = 0; n < 2; ++n) {
            const int byteoff = ((wc * 32 + n * 16 + l15) * 64 + kq * 16) ^ xorv;
            bfr[n] = *reinterpret_cast<const s16x8*>(&Bs[buf][byteoff >> 1]);
        }
        #pragma unroll
        for (int m = 0; m < 4; ++m)
            #pragma unroll
            for (int n = 0; n < 2; ++n)
                acc[m][n] = __builtin_amdgcn_mfma_f32_16x16x32_bf16(af[m], bfr[n], acc[m][n], 0, 0, 0);
    };

    // counted-vmcnt 2-buffer pipeline (T4): never drain to 0 in steady state
    stage(0, 0);
    stage(1, 32);
    int cur = 0;
    #pragma unroll 1
    for (int t = 0; t < NT; ++t) {
        if (t < NT - 1) {
            asm volatile("s_waitcnt vmcnt(3)" ::: "memory");  // tile t's 3 loads done
        } else {
            asm volatile("s_waitcnt vmcnt(0)" ::: "memory");
        }
        __builtin_amdgcn_s_barrier();
        compute(cur);
        if (t + 2 < NT) {
            __builtin_amdgcn_s_barrier();   // all waves done reading buf `cur`
            stage(cur, (t + 2) * 32);
        }
        cur ^= 1;
    }

    #pragma unroll
    for (int m = 0; m < 4; ++m) {
        const int rbase = row0 + wr * 64 + m * 16 + kq * 4;
        float dr[4];
        #pragma unroll
        for (int j = 0; j < 4; ++j) dr[j] = d_is[rbase + j];
        #pragma unroll
        for (int n = 0; n < 2; ++n) {
            const int col = col0 + wc * 32 + n * 16 + l15;
            u16x4 pk;
            #pragma unroll
            for (int j = 0; j < 4; ++j) pk[j] = (unsigned short)f2bf(dr[j] * acc[m][n][j]);
            *reinterpret_cast<u16x4*>(&psT[(size_t)col * NN + rbase]) = pk;
        }
    }
}

// ---------- Kernel 5: prop2 — 128x128, counted-vmcnt pipeline, split-K=4 ----------
__global__ __launch_bounds__(256, 4) void prop2_kernel(
    const short* __restrict__ adjB, const short* __restrict__ psT,
    short* __restrict__ Pb0, short* __restrict__ Pb1,
    short* __restrict__ Pb2, float* __restrict__ Pf) {
    constexpr int Ksub = NN / 4;   // 2048
    constexpr int NT = Ksub / 32;  // 64
    __shared__ short As[2][4096];
    __shared__ short Bs[2][4096];

    const int tid = threadIdx.x;
    const int lin = blockIdx.x;
    const int swz = (lin & 7) * 128 + (lin >> 3);
    const int col0 = (swz & 3) * 128;
    const int ks = (swz >> 2) & 3;
    const int row0 = (swz >> 4) * 128;

    const int lane = tid & 63;
    const int wv = tid >> 6;
    const int wr = wv >> 1, wc = wv & 1;   // wave tile 64x64
    const int l15 = lane & 15;
    const int kq = lane >> 4;
    const int xorv = (l15 & 12) << 2;

    int arow[2], acoff[2];
    #pragma unroll
    for (int i = 0; i < 2; ++i) {
        const int slot = i * 256 + tid;
        const int P = (slot << 4) ^ (slot & 48);
        arow[i] = P >> 6;
        acoff[i] = (P & 63) >> 1;
    }
    const size_t kbase = (size_t)ks * Ksub;
    const short* Ab = adjB + (size_t)row0 * NN + kbase;
    const short* Bb = psT + (size_t)col0 * NN + kbase;

    auto stage = [&](int buf, int k0) {  // 4 vmem instructions per call
        #pragma unroll
        for (int i = 0; i < 2; ++i) {
            const short* src = Ab + (size_t)arow[i] * NN + k0 + acoff[i];
            short* dst = &As[buf][(i * 256 + (tid & 192)) * 8];
            __builtin_amdgcn_global_load_lds(
                (const __attribute__((address_space(1))) unsigned int*)src,
                (__attribute__((address_space(3))) unsigned int*)dst, 16, 0, 0);
        }
        #pragma unroll
        for (int i = 0; i < 2; ++i) {
            const short* src = Bb + (size_t)arow[i] * NN + k0 + acoff[i];
            short* dst = &Bs[buf][(i * 256 + (tid & 192)) * 8];
            __builtin_amdgcn_global_load_lds(
                (const __attribute__((address_space(1))) unsigned int*)src,
                (__attribute__((address_space(3))) unsigned int*)dst, 16, 0, 0);
        }
    };

    f32x4 acc[4][4] = {};
    auto compute = [&](int buf) {
        s16x8 af[4], bfr[4];
        #pragma unroll
        for (int m = 0; m < 4; ++m) {
            const int byteoff = ((wr * 64 + m * 16 + l15) * 64 + kq * 16) ^ xorv;
            af[m] = *reinterpret_cast<const s16x8*>(&As[buf][byteoff >> 1]);
        }
        #pragma unroll
        for (int n = 0; n < 4; ++n) {
            const int byteoff = ((wc * 64 + n * 16 + l15) * 64 + kq * 16) ^ xorv;
            bfr[n] = *reinterpret_cast<const s16x8*>(&Bs[buf][byteoff >> 1]);
        }
        #pragma unroll
        for (int m = 0; m < 4; ++m)
            #pragma unroll
            for (int n = 0; n < 4; ++n)
                acc[m][n] = __builtin_amdgcn_mfma_f32_16x16x32_bf16(af[m], bfr[n], acc[m][n], 0, 0, 0);
    };

    // counted-vmcnt 2-buffer pipeline (T4)
    stage(0, 0);
    stage(1, 32);
    int cur = 0;
    #pragma unroll 1
    for (int t = 0; t < NT; ++t) {
        if (t < NT - 1) {
            asm volatile("s_waitcnt vmcnt(4)" ::: "memory");  // tile t's 4 loads done
        } else {
            asm volatile("s_waitcnt vmcnt(0)" ::: "memory");
        }
        __builtin_amdgcn_s_barrier();
        compute(cur);
        if (t + 2 < NT) {
            __builtin_amdgcn_s_barrier();   // all waves done reading buf `cur`
            stage(cur, (t + 2) * 32);
        }
        cur ^= 1;
    }

    if (ks == 3) {
        #pragma unroll
        for (int m = 0; m < 4; ++m) {
            const int rbase = row0 + wr * 64 + m * 16 + kq * 4;
            #pragma unroll
            for (int n = 0; n < 4; ++n) {
                const int col = col0 + wc * 64 + n * 16 + l15;
                #pragma unroll
                for (int j = 0; j < 4; ++j)
                    Pf[(size_t)(rbase + j) * FOUT + col] = acc[m][n][j];
            }
        }
    } else {
        short* Pt = (ks == 0) ? Pb0 : (ks == 1) ? Pb1 : Pb2;
        #pragma unroll
        for (int m = 0; m < 4; ++m) {
            const int rbase = row0 + wr * 64 + m * 16 + kq * 4;
            #pragma unroll
            for (int n = 0; n < 4; ++n) {
                const int col = col0 + wc * 64 + n * 16 + l15;
                #pragma unroll
                for (int j = 0; j < 4; ++j)
                    Pt[(size_t)(rbase + j) * FOUT + col] = f2bf(acc[m][n][j]);
            }
        }
    }
}

// ---------- Kernel 6: out = relu(d*(Pb0+Pb1+Pb2+Pf + psT^T) + b) ----------
__global__ __launch_bounds__(256) void ep4_kernel(
    const short* __restrict__ Pb0, const short* __restrict__ Pb1,
    const short* __restrict__ Pb2, float* __restrict__ out,
    const short* __restrict__ psT, const float* __restrict__ d_is,
    const float* __restrict__ bias) {
    const int col0 = blockIdx.x * 128;
    const int row0 = blockIdx.y * 32;
    const int t = threadIdx.x;
    const int c = col0 + (t & 31) * 4;
    const float4 bb = *reinterpret_cast<const float4*>(&bias[c]);
    #pragma unroll
    for (int it = 0; it < 4; ++it) {
        const int r = row0 + (t >> 5) + it * 8;
        const size_t idx = (size_t)r * FOUT + c;
        const u16x4 a = *reinterpret_cast<const u16x4*>(&Pb0[idx]);
        const u16x4 b4 = *reinterpret_cast<const u16x4*>(&Pb1[idx]);
        const u16x4 c4 = *reinterpret_cast<const u16x4*>(&Pb2[idx]);
        const float4 d4 = *reinterpret_cast<const float4*>(&out[idx]);
        const float dr = d_is[r];
        float s[4], o4[4];
        #pragma unroll
        for (int j = 0; j < 4; ++j) s[j] = bf2f(psT[(size_t)(c + j) * NN + r]);
        const float dd[4] = {d4.x, d4.y, d4.z, d4.w};
        const float bbv[4] = {bb.x, bb.y, bb.z, bb.w};
        #pragma unroll
        for (int j = 0; j < 4; ++j) {
            const float sum = ((bf2f((short)a[j]) + bf2f((short)b4[j])) +
                               (bf2f((short)c4[j]) + dd[j])) + s[j];
            o4[j] = fmaxf(dr * sum + bbv[j], 0.f);
        }
        float4 o = {o4[0], o4[1], o4[2], o4[3]};
        *reinterpret_cast<float4*>(&out[idx]) = o;
    }
}

// ---------- Fallback kernels (small-ws path) ----------
template<int KLEN, int MODE>
__global__ __launch_bounds__(256, 4) void gemm_kernel(
    const float* __restrict__ A, const short* __restrict__ B,
    const float* __restrict__ d_is,
    short* __restrict__ psT,
    float* __restrict__ P0, float* __restrict__ P1) {
    constexpr int KS = (MODE == 1) ? 2 : 1;
    constexpr int Ksub = KLEN / KS;
    constexpr int NT = Ksub / 32;
    constexpr int LDA = 40;
    __shared__ short As[2][128 * LDA];
    __shared__ short Bs[2][64 * LDA];

    const int tid = threadIdx.x;
    const int nchunk = gridDim.x >> 3;
    const int lin = blockIdx.x;
    const int swz = (lin & 7) * nchunk + (lin >> 3);
    const int col0 = (swz & 7) * 64;
    const int yp = (swz >> 3) & 63;
    const int ks = swz >> 9;
    const int row0 = yp * 128;
    const int kbase = ks * Ksub;

    const int lane = tid & 63;
    const int wv = tid >> 6;
    const int wr = wv >> 1, wc = wv & 1;
    const int l15 = lane & 15;
    const int koff = (lane >> 4) * 8;

    const int ar = tid >> 1, ak = (tid & 1) * 16;
    const float* Abase = A + (size_t)(row0 + ar) * KLEN + kbase + ak;
    const int br = tid >> 2, bk = (tid & 3) * 8;
    const short* Bbase = B + (size_t)(col0 + br) * KLEN + kbase + bk;

    float4 qa0, qa1, qa2, qa3;
    s16x8 qb;
    auto loadG = [&](int k0) {
        const float4* p = reinterpret_cast<const float4*>(Abase + k0);
        qa0 = p[0]; qa1 = p[1]; qa2 = p[2]; qa3 = p[3];
        qb = *reinterpret_cast<const s16x8*>(Bbase + k0);
    };
    auto writeL = [&](int buf) {
        const float a[16] = {qa0.x, qa0.y, qa0.z, qa0.w, qa1.x, qa1.y, qa1.z, qa1.w,
                             qa2.x, qa2.y, qa2.z, qa2.w, qa3.x, qa3.y, qa3.z, qa3.w};
        s16x8 v0, v1;
        #pragma unroll
        for (int e = 0; e < 8; ++e) { v0[e] = f2bf(a[e]); v1[e] = f2bf(a[8 + e]); }
        *reinterpret_cast<s16x8*>(&As[buf][ar * LDA + ak]) = v0;
        *reinterpret_cast<s16x8*>(&As[buf][ar * LDA + ak + 8]) = v1;
        *reinterpret_cast<s16x8*>(&Bs[buf][br * LDA + bk]) = qb;
    };

    f32x4 acc[4][2] = {};
    auto compute = [&](int buf) {
        s16x8 af[4], bfr[2];
        #pragma unroll
        for (int m = 0; m < 4; ++m)
            af[m] = *reinterpret_cast<const s16x8*>(&As[buf][(wr * 64 + m * 16 + l15) * LDA + koff]);
        #pragma unroll
        for (int n = 0; n < 2; ++n)
            bfr[n] = *reinterpret_cast<const s16x8*>(&Bs[buf][(wc * 32 + n * 16 + l15) * LDA + koff]);
        #pragma unroll
        for (int m = 0; m < 4; ++m)
            #pragma unroll
            for (int n = 0; n < 2; ++n)
                acc[m][n] = __builtin_amdgcn_mfma_f32_16x16x32_bf16(af[m], bfr[n], acc[m][n], 0, 0, 0);
    };

    loadG(0);
    writeL(0);
    __syncthreads();
    int cur = 0;
    for (int t = 0; t < NT; ++t) {
        if (t + 1 < NT) loadG((t + 1) * 32);
        compute(cur);
        if (t + 1 < NT) writeL(cur ^ 1);
        __syncthreads();
        cur ^= 1;
    }

    if (MODE == 0) {
        #pragma unroll
        for (int m = 0; m < 4; ++m) {
            const int rbase = row0 + wr * 64 + m * 16 + (lane >> 4) * 4;
            float dr[4];
            #pragma unroll
            for (int j = 0; j < 4; ++j) dr[j] = d_is[rbase + j];
            #pragma unroll
            for (int n = 0; n < 2; ++n) {
                const int col = col0 + wc * 32 + n * 16 + l15;
                u16x4 pk;
                #pragma unroll
                for (int j = 0; j < 4; ++j) pk[j] = (unsigned short)f2bf(dr[j] * acc[m][n][j]);
                *reinterpret_cast<u16x4*>(&psT[(size_t)col * NN + rbase]) = pk;
            }
        }
    } else {
        float* tgt = (ks == 0) ? P0 : P1;
        #pragma unroll
        for (int m = 0; m < 4; ++m) {
            const int rbase = row0 + wr * 64 + m * 16 + (lane >> 4) * 4;
            #pragma unroll
            for (int n = 0; n < 2; ++n) {
                const int col = col0 + wc * 32 + n * 16 + l15;
                f32x4 v = acc[m][n];
                if (ks == 0) {
                    const u16x4 sv = *reinterpret_cast<const u16x4*>(&psT[(size_t)col * NN + rbase]);
                    #pragma unroll
                    for (int j = 0; j < 4; ++j) v[j] += bf2f((short)sv[j]);
                }
                #pragma unroll
                for (int j = 0; j < 4; ++j)
                    tgt[(size_t)(rbase + j) * FOUT + col] = v[j];
            }
        }
    }
}

__global__ __launch_bounds__(256) void ep_kernel(const float* __restrict__ P0,
                                                 float* __restrict__ out,
                                                 const float* __restrict__ d_is,
                                                 const float* __restrict__ bias) {
    const size_t idx = ((size_t)blockIdx.x * 256 + threadIdx.x) * 4;
    const int row = (int)(idx >> 9);
    const int col = (int)(idx & 511);
    const float4 p0 = *reinterpret_cast<const float4*>(&P0[idx]);
    const float4 p1 = *reinterpret_cast<const float4*>(&out[idx]);
    const float4 bb = *reinterpret_cast<const float4*>(&bias[col]);
    const float dr = d_is[row];
    float4 o;
    o.x = fmaxf(dr * (p0.x + p1.x) + bb.x, 0.f);
    o.y = fmaxf(dr * (p0.y + p1.y) + bb.y, 0.f);
    o.z = fmaxf(dr * (p0.z + p1.z) + bb.z, 0.f);
    o.w = fmaxf(dr * (p0.w + p1.w) + bb.w, 0.f);
    *reinterpret_cast<float4*>(&out[idx]) = o;
}

extern "C" void kernel_launch(void* const* d_in, const int* in_sizes, int n_in,
                              void* d_out, int out_size, void* d_ws, size_t ws_size,
                              hipStream_t stream) {
    const float* x   = (const float*)d_in[0];
    const float* adj = (const float*)d_in[1];
    const float* W   = (const float*)d_in[2];
    const float* b   = (const float*)d_in[3];
    float* out = (float*)d_out;

    // Path A layout: psT | WT | xB | Pb0 | Pb1 | Pb2 | dis | adjB
    const size_t NEED = (size_t)FOUT * NN * 2 + (size_t)FOUT * FIN * 2
                      + (size_t)NN * FIN * 2 + 3ull * NN * FOUT * 2
                      + NN * 4 + (size_t)NN * NN * 2;

    if (ws_size >= NEED) {
        short* psT = (short*)d_ws;
        short* WT  = psT + (size_t)FOUT * NN;
        short* xB  = WT + (size_t)FOUT * FIN;
        short* Pb0 = xB + (size_t)NN * FIN;
        short* Pb1 = Pb0 + (size_t)NN * FOUT;
        short* Pb2 = Pb1 + (size_t)NN * FOUT;
        float* dis = (float*)(Pb2 + (size_t)NN * FOUT);
        short* adjB = (short*)(dis + NN);

        hipLaunchKernelGGL(rowsum_cvt_kernel, dim3(NN), dim3(256), 0, stream, adj, adjB, dis);
        hipLaunchKernelGGL(cvt_x_kernel, dim3(NN * FIN / 2048), dim3(256), 0, stream, x, xB);
        hipLaunchKernelGGL(wt_kernel, dim3(8, 16), dim3(256), 0, stream, W, WT);
        hipLaunchKernelGGL(xwg_kernel, dim3(512), dim3(256), 0, stream, xB, WT, dis, psT);
        hipLaunchKernelGGL(prop2_kernel, dim3(1024), dim3(256), 0, stream,
                           adjB, psT, Pb0, Pb1, Pb2, out);
        hipLaunchKernelGGL(ep4_kernel, dim3(4, 256), dim3(256), 0, stream,
                           Pb0, Pb1, Pb2, out, psT, dis, b);
    } else {
        short* psT = (short*)d_ws;
        short* WT  = psT + (size_t)FOUT * NN;
        float* P0  = (float*)(WT + (size_t)FOUT * FIN);
        float* dis = P0 + (size_t)NN * FOUT;

        hipLaunchKernelGGL(rowsum_kernel, dim3(NN), dim3(256), 0, stream, adj, dis);
        hipLaunchKernelGGL(wt_kernel, dim3(8, 16), dim3(256), 0, stream, W, WT);
        hipLaunchKernelGGL((gemm_kernel<FIN, 0>), dim3(512), dim3(256), 0, stream,
                           x, WT, dis, psT, nullptr, nullptr);
        hipLaunchKernelGGL((gemm_kernel<NN, 1>), dim3(1024), dim3(256), 0, stream,
                           adj, psT, dis, psT, P0, out);
        hipLaunchKernelGGL(ep_kernel, dim3(NN * FOUT / 1024), dim3(256), 0, stream,
                           P0, out, dis, b);
    }
}

// Round 7
// 191.972 us; speedup vs baseline: 6.1864x; 1.1361x over previous
//
#include <hip/hip_runtime.h>
#include <stdint.h>

#define NN 8192
#define FIN 1024
#define FOUT 512

typedef __attribute__((ext_vector_type(4))) float f32x4;
typedef __attribute__((ext_vector_type(8))) short s16x8;
typedef __attribute__((ext_vector_type(4))) unsigned short u16x4;

__device__ __forceinline__ short f2bf(float f) {
    return __builtin_bit_cast(short, static_cast<__bf16>(f));
}
__device__ __forceinline__ float bf2f(short s) {
    return (float)__builtin_bit_cast(__bf16, s);
}

// ---------- Kernel 1 (path A): fused prep ----------
// blocks [0,8192): rowsum+cvt adj->adjB ; [8192,12288): x->xB ; [12288,12416): W->WT
__global__ __launch_bounds__(256) void prep_kernel(const float* __restrict__ adj,
                                                   short* __restrict__ adjB,
                                                   float* __restrict__ d_is,
                                                   const float* __restrict__ x,
                                                   short* __restrict__ xB,
                                                   const float* __restrict__ W,
                                                   short* __restrict__ WT) {
    __shared__ float red[4];
    __shared__ float T[64][68];
    const int b = blockIdx.x;
    const int t = threadIdx.x;
    if (b < NN) {
        const int row = b;
        const float4* a = reinterpret_cast<const float4*>(adj + (size_t)row * NN);
        u16x4* ob = reinterpret_cast<u16x4*>(adjB + (size_t)row * NN);
        float s = 0.f;
        #pragma unroll 2
        for (int j = t; j < NN / 4; j += 256) {
            float4 v = a[j];
            s += (v.x + v.y) + (v.z + v.w);
            u16x4 p;
            p[0] = (unsigned short)f2bf(v.x); p[1] = (unsigned short)f2bf(v.y);
            p[2] = (unsigned short)f2bf(v.z); p[3] = (unsigned short)f2bf(v.w);
            ob[j] = p;
        }
        #pragma unroll
        for (int off = 32; off > 0; off >>= 1) s += __shfl_down(s, off, 64);
        if ((t & 63) == 0) red[t >> 6] = s;
        __syncthreads();
        if (t == 0) {
            const float d = red[0] + red[1] + red[2] + red[3] + 1.0f;
            d_is[row] = 1.0f / sqrtf(d);
        }
    } else if (b < NN + 4096) {
        const size_t i = ((size_t)(b - NN) * 256 + t) * 8;
        const float4 v0 = *reinterpret_cast<const float4*>(&x[i]);
        const float4 v1 = *reinterpret_cast<const float4*>(&x[i + 4]);
        s16x8 o;
        o[0] = f2bf(v0.x); o[1] = f2bf(v0.y); o[2] = f2bf(v0.z); o[3] = f2bf(v0.w);
        o[4] = f2bf(v1.x); o[5] = f2bf(v1.y); o[6] = f2bf(v1.z); o[7] = f2bf(v1.w);
        *reinterpret_cast<s16x8*>(&xB[i]) = o;
    } else {
        const int bid = b - NN - 4096;
        const int wc = bid & 7;
        const int wk = bid >> 3;
        const int cc = (t & 15) * 4;
        #pragma unroll
        for (int i = 0; i < 4; ++i) {
            const int rr = (t >> 4) + i * 16;
            *reinterpret_cast<float4*>(&T[rr][cc]) =
                *reinterpret_cast<const float4*>(&W[(size_t)(wk * 64 + rr) * FOUT + wc * 64 + cc]);
        }
        __syncthreads();
        const int a = t >> 2;
        const int b0 = (t & 3) * 16;
        s16x8 v0, v1;
        #pragma unroll
        for (int e = 0; e < 8; ++e) { v0[e] = f2bf(T[b0 + e][a]); v1[e] = f2bf(T[b0 + 8 + e][a]); }
        short* dst = &WT[(size_t)(wc * 64 + a) * FIN + wk * 64 + b0];
        *reinterpret_cast<s16x8*>(dst) = v0;
        *reinterpret_cast<s16x8*>(dst + 8) = v1;
    }
}

// ---------- Kernel 1B (fallback): rowsum only ----------
__global__ __launch_bounds__(256) void rowsum_kernel(const float* __restrict__ adj,
                                                     float* __restrict__ d_is) {
    const int row = blockIdx.x;
    const float4* a = reinterpret_cast<const float4*>(adj + (size_t)row * NN);
    float s = 0.f;
    #pragma unroll 4
    for (int j = threadIdx.x; j < NN / 4; j += 256) {
        float4 v = a[j];
        s += (v.x + v.y) + (v.z + v.w);
    }
    #pragma unroll
    for (int off = 32; off > 0; off >>= 1) s += __shfl_down(s, off, 64);
    __shared__ float red[4];
    if ((threadIdx.x & 63) == 0) red[threadIdx.x >> 6] = s;
    __syncthreads();
    if (threadIdx.x == 0) {
        const float d = red[0] + red[1] + red[2] + red[3] + 1.0f;
        d_is[row] = 1.0f / sqrtf(d);
    }
}

// ---------- Kernel wt (fallback) ----------
__global__ __launch_bounds__(256) void wt_kernel(const float* __restrict__ W,
                                                 short* __restrict__ WT) {
    __shared__ float T[64][68];
    const int wc = blockIdx.x;
    const int wk = blockIdx.y;
    const int t = threadIdx.x;
    const int cc = (t & 15) * 4;
    #pragma unroll
    for (int i = 0; i < 4; ++i) {
        const int rr = (t >> 4) + i * 16;
        *reinterpret_cast<float4*>(&T[rr][cc]) =
            *reinterpret_cast<const float4*>(&W[(size_t)(wk * 64 + rr) * FOUT + wc * 64 + cc]);
    }
    __syncthreads();
    const int a = t >> 2;
    const int b0 = (t & 3) * 16;
    s16x8 v0, v1;
    #pragma unroll
    for (int e = 0; e < 8; ++e) { v0[e] = f2bf(T[b0 + e][a]); v1[e] = f2bf(T[b0 + 8 + e][a]); }
    short* dst = &WT[(size_t)(wc * 64 + a) * FIN + wk * 64 + b0];
    *reinterpret_cast<s16x8*>(dst) = v0;
    *reinterpret_cast<s16x8*>(dst + 8) = v1;
}

// ---------- Kernel 2: xwg — glds-staged bf16 GEMM, counted-vmcnt (round-6) ----------
__global__ __launch_bounds__(256, 4) void xwg_kernel(const short* __restrict__ xB,
                                                     const short* __restrict__ WT,
                                                     const float* __restrict__ d_is,
                                                     short* __restrict__ psT) {
    constexpr int NT = FIN / 32;  // 32
    __shared__ short As[2][4096];
    __shared__ short Bs[2][2048];

    const int tid = threadIdx.x;
    const int lin = blockIdx.x;
    const int swz = (lin & 7) * 64 + (lin >> 3);
    const int col0 = (swz & 7) * 64;
    const int row0 = (swz >> 3) * 128;

    const int lane = tid & 63;
    const int wv = tid >> 6;
    const int wr = wv >> 1, wc = wv & 1;
    const int l15 = lane & 15;
    const int kq = lane >> 4;
    const int xorv = (l15 & 12) << 2;

    int arow[2], acoff[2];
    #pragma unroll
    for (int i = 0; i < 2; ++i) {
        const int slot = i * 256 + tid;
        const int P = (slot << 4) ^ (slot & 48);
        arow[i] = P >> 6;
        acoff[i] = (P & 63) >> 1;
    }
    const short* Ab = xB + (size_t)row0 * FIN;
    const short* Bb = WT + (size_t)col0 * FIN;

    auto stage = [&](int buf, int k0) {
        #pragma unroll
        for (int i = 0; i < 2; ++i) {
            const short* src = Ab + (size_t)arow[i] * FIN + k0 + acoff[i];
            short* dst = &As[buf][(i * 256 + (tid & 192)) * 8];
            __builtin_amdgcn_global_load_lds(
                (const __attribute__((address_space(1))) unsigned int*)src,
                (__attribute__((address_space(3))) unsigned int*)dst, 16, 0, 0);
        }
        {
            const short* src = Bb + (size_t)arow[0] * FIN + k0 + acoff[0];
            short* dst = &Bs[buf][(tid & 192) * 8];
            __builtin_amdgcn_global_load_lds(
                (const __attribute__((address_space(1))) unsigned int*)src,
                (__attribute__((address_space(3))) unsigned int*)dst, 16, 0, 0);
        }
    };

    f32x4 acc[4][2] = {};
    auto compute = [&](int buf) {
        s16x8 af[4], bfr[2];
        #pragma unroll
        for (int m = 0; m < 4; ++m) {
            const int byteoff = ((wr * 64 + m * 16 + l15) * 64 + kq * 16) ^ xorv;
            af[m] = *reinterpret_cast<const s16x8*>(&As[buf][byteoff >> 1]);
        }
        #pragma unroll
        for (int n = 0; n < 2; ++n) {
            const int byteoff = ((wc * 32 + n * 16 + l15) * 64 + kq * 16) ^ xorv;
            bfr[n] = *reinterpret_cast<const s16x8*>(&Bs[buf][byteoff >> 1]);
        }
        #pragma unroll
        for (int m = 0; m < 4; ++m)
            #pragma unroll
            for (int n = 0; n < 2; ++n)
                acc[m][n] = __builtin_amdgcn_mfma_f32_16x16x32_bf16(af[m], bfr[n], acc[m][n], 0, 0, 0);
    };

    stage(0, 0);
    stage(1, 32);
    int cur = 0;
    #pragma unroll 1
    for (int t = 0; t < NT; ++t) {
        if (t < NT - 1) {
            asm volatile("s_waitcnt vmcnt(3)" ::: "memory");
        } else {
            asm volatile("s_waitcnt vmcnt(0)" ::: "memory");
        }
        __builtin_amdgcn_s_barrier();
        compute(cur);
        if (t + 2 < NT) {
            __builtin_amdgcn_s_barrier();
            stage(cur, (t + 2) * 32);
        }
        cur ^= 1;
    }

    #pragma unroll
    for (int m = 0; m < 4; ++m) {
        const int rbase = row0 + wr * 64 + m * 16 + kq * 4;
        float dr[4];
        #pragma unroll
        for (int j = 0; j < 4; ++j) dr[j] = d_is[rbase + j];
        #pragma unroll
        for (int n = 0; n < 2; ++n) {
            const int col = col0 + wc * 32 + n * 16 + l15;
            u16x4 pk;
            #pragma unroll
            for (int j = 0; j < 4; ++j) pk[j] = (unsigned short)f2bf(dr[j] * acc[m][n][j]);
            *reinterpret_cast<u16x4*>(&psT[(size_t)col * NN + rbase]) = pk;
        }
    }
}

// ---------- Kernel 3: prop3 — 256x256 8-phase, counted vmcnt, split-K=4 ----------
// A = adjB [8192][8192] bf16, B = psT [512][8192] bf16. 512 thr, 8 waves (2x4).
// LDS 128 KB dynamic: 2 buf x { A[2 kh][256r][32k] | B[2 kh][256r][32k] }.
__global__ __launch_bounds__(512, 1) void prop3_kernel(
    const short* __restrict__ adjB, const short* __restrict__ psT,
    short* __restrict__ Pb0, short* __restrict__ Pb1,
    short* __restrict__ Pb2, float* __restrict__ Pf) {
    extern __shared__ short L[];  // 65536 shorts = 128 KB

    const int tid = threadIdx.x;
    const int lin = blockIdx.x;
    const int swz = (lin & 7) * 32 + (lin >> 3);   // bijective XCD chunking (256 = 8*32)
    const int col0 = (swz & 1) * 256;
    const int ks = (swz >> 1) & 3;
    const int row0 = (swz >> 3) * 256;

    const int lane = tid & 63;
    const int wv = tid >> 6;        // 0..7
    const int wr = wv >> 2;         // 0..1: row half (128 rows)
    const int wc = wv & 3;          // 0..3: col quarter (64 cols)
    const int l15 = lane & 15;
    const int kq = lane >> 4;
    const int xorv = (l15 & 12) << 2;

    // staging source indices (inverse-swizzled): slot = i*512 + tid over a 16 KB half
    int srow[2], scol[2];
    #pragma unroll
    for (int i = 0; i < 2; ++i) {
        const int slot = i * 512 + tid;
        const int P = (slot << 4) ^ (slot & 48);
        srow[i] = P >> 6;          // 0..255
        scol[i] = (P & 63) >> 1;   // 0..31
    }
    const size_t kbase = (size_t)ks * 2048;
    const short* Ab = adjB + (size_t)row0 * NN + kbase;
    const short* Bb = psT + (size_t)col0 * NN + kbase;

    // stage one half-tile (16 KB): op 0=A,1=B; k-half kh of tile t into buffer buf
    auto stageH = [&](int buf, int op, int kh, int t) {
        const short* s0 = op ? Bb : Ab;
        const int k0 = t * 64 + kh * 32;
        short* base = &L[buf * 32768 + op * 16384 + kh * 8192];
        #pragma unroll
        for (int i = 0; i < 2; ++i) {
            const short* src = s0 + (size_t)srow[i] * NN + k0 + scol[i];
            short* dst = base + (i * 512 + (tid & 448)) * 8;
            __builtin_amdgcn_global_load_lds(
                (const __attribute__((address_space(1))) unsigned int*)src,
                (__attribute__((address_space(3))) unsigned int*)dst, 16, 0, 0);
        }
    };

    f32x4 acc[8][4] = {};

#define LDFRAG(BASE, ROW) \
    (*reinterpret_cast<const s16x8*>(&(BASE)[((((ROW) * 64 + kq * 16)) ^ xorv) >> 1]))

#define PHASE(BUF, KH, QM, STAGE_STMT, VM_STMT)                                     \
    do {                                                                            \
        const short* Ah_ = &L[(BUF) * 32768 + (KH) * 8192];                         \
        const short* Bh_ = &L[(BUF) * 32768 + 16384 + (KH) * 8192];                 \
        s16x8 af_[4], bg_[4];                                                       \
        _Pragma("unroll")                                                           \
        for (int m = 0; m < 4; ++m)                                                 \
            af_[m] = LDFRAG(Ah_, wr * 128 + (QM) * 64 + m * 16 + l15);              \
        _Pragma("unroll")                                                           \
        for (int n = 0; n < 4; ++n)                                                 \
            bg_[n] = LDFRAG(Bh_, wc * 64 + n * 16 + l15);                           \
        STAGE_STMT;                                                                 \
        asm volatile("" ::: "memory");                                              \
        __builtin_amdgcn_s_barrier();                                               \
        __builtin_amdgcn_s_setprio(1);                                              \
        _Pragma("unroll")                                                           \
        for (int m = 0; m < 4; ++m)                                                 \
            _Pragma("unroll")                                                       \
            for (int n = 0; n < 4; ++n)                                             \
                acc[(QM) * 4 + m][n] = __builtin_amdgcn_mfma_f32_16x16x32_bf16(     \
                    af_[m], bg_[n], acc[(QM) * 4 + m][n], 0, 0, 0);                 \
        __builtin_amdgcn_s_setprio(0);                                              \
        VM_STMT;                                                                    \
        asm volatile("" ::: "memory");                                              \
        __builtin_amdgcn_s_barrier();                                               \
    } while (0)

#define VM4 asm volatile("s_waitcnt vmcnt(4)" ::: "memory")
#define VM0 asm volatile("s_waitcnt vmcnt(0)" ::: "memory")

    // prologue: tile0 all 4 halves + tile1 {A0,B0}  (12 vmem instr/wave)
    stageH(0, 0, 0, 0); stageH(0, 1, 0, 0);
    stageH(0, 0, 1, 0); stageH(0, 1, 1, 0);
    stageH(1, 0, 0, 1); stageH(1, 1, 0, 1);
    asm volatile("s_waitcnt vmcnt(8)" ::: "memory");   // tile0 {A0,B0} landed
    __builtin_amdgcn_s_barrier();

    // t = 0 (buf 0): t1 {A0,B0} pre-staged; issue t1 {A1,B1} at phases 2,3
    PHASE(0, 0, 0, (void)0,             (void)0);
    PHASE(0, 0, 1, (void)0,             VM4);
    PHASE(0, 1, 0, stageH(1, 0, 1, 1),  (void)0);
    PHASE(0, 1, 1, stageH(1, 1, 1, 1),  VM4);

    // steady t = 1..30
    #pragma unroll 1
    for (int t = 1; t <= 30; ++t) {
        const int buf = t & 1, nb = buf ^ 1, tn = t + 1;
        PHASE(buf, 0, 0, stageH(nb, 0, 0, tn), (void)0);
        PHASE(buf, 0, 1, stageH(nb, 1, 0, tn), VM4);
        PHASE(buf, 1, 0, stageH(nb, 0, 1, tn), (void)0);
        PHASE(buf, 1, 1, stageH(nb, 1, 1, tn), VM4);
    }

    // t = 31 (buf 1): no more staging
    PHASE(1, 0, 0, (void)0, (void)0);
    PHASE(1, 0, 1, (void)0, VM0);
    PHASE(1, 1, 0, (void)0, (void)0);
    PHASE(1, 1, 1, (void)0, (void)0);

    // epilogue: raw partials (C/D map: col = lane&15, row = kq*4 + j)
    if (ks == 3) {
        #pragma unroll
        for (int mi = 0; mi < 8; ++mi) {
            const int rbase = row0 + wr * 128 + mi * 16 + kq * 4;
            #pragma unroll
            for (int n = 0; n < 4; ++n) {
                const int col = col0 + wc * 64 + n * 16 + l15;
                #pragma unroll
                for (int j = 0; j < 4; ++j)
                    Pf[(size_t)(rbase + j) * FOUT + col] = acc[mi][n][j];
            }
        }
    } else {
        short* Pt = (ks == 0) ? Pb0 : (ks == 1) ? Pb1 : Pb2;
        #pragma unroll
        for (int mi = 0; mi < 8; ++mi) {
            const int rbase = row0 + wr * 128 + mi * 16 + kq * 4;
            #pragma unroll
            for (int n = 0; n < 4; ++n) {
                const int col = col0 + wc * 64 + n * 16 + l15;
                #pragma unroll
                for (int j = 0; j < 4; ++j)
                    Pt[(size_t)(rbase + j) * FOUT + col] = f2bf(acc[mi][n][j]);
            }
        }
    }
#undef PHASE
#undef LDFRAG
#undef VM4
#undef VM0
}

// ---------- Kernel 4: out = relu(d*(Pb0+Pb1+Pb2+Pf + psT^T) + b) ----------
__global__ __launch_bounds__(256) void ep4_kernel(
    const short* __restrict__ Pb0, const short* __restrict__ Pb1,
    const short* __restrict__ Pb2, float* __restrict__ out,
    const short* __restrict__ psT, const float* __restrict__ d_is,
    const float* __restrict__ bias) {
    const int col0 = blockIdx.x * 128;
    const int row0 = blockIdx.y * 32;
    const int t = threadIdx.x;
    const int c = col0 + (t & 31) * 4;
    const float4 bb = *reinterpret_cast<const float4*>(&bias[c]);
    #pragma unroll
    for (int it = 0; it < 4; ++it) {
        const int r = row0 + (t >> 5) + it * 8;
        const size_t idx = (size_t)r * FOUT + c;
        const u16x4 a = *reinterpret_cast<const u16x4*>(&Pb0[idx]);
        const u16x4 b4 = *reinterpret_cast<const u16x4*>(&Pb1[idx]);
        const u16x4 c4 = *reinterpret_cast<const u16x4*>(&Pb2[idx]);
        const float4 d4 = *reinterpret_cast<const float4*>(&out[idx]);
        const float dr = d_is[r];
        float s[4], o4[4];
        #pragma unroll
        for (int j = 0; j < 4; ++j) s[j] = bf2f(psT[(size_t)(c + j) * NN + r]);
        const float dd[4] = {d4.x, d4.y, d4.z, d4.w};
        const float bbv[4] = {bb.x, bb.y, bb.z, bb.w};
        #pragma unroll
        for (int j = 0; j < 4; ++j) {
            const float sum = ((bf2f((short)a[j]) + bf2f((short)b4[j])) +
                               (bf2f((short)c4[j]) + dd[j])) + s[j];
            o4[j] = fmaxf(dr * sum + bbv[j], 0.f);
        }
        float4 o = {o4[0], o4[1], o4[2], o4[3]};
        *reinterpret_cast<float4*>(&out[idx]) = o;
    }
}

// ---------- Fallback kernels (small-ws path) ----------
template<int KLEN, int MODE>
__global__ __launch_bounds__(256, 4) void gemm_kernel(
    const float* __restrict__ A, const short* __restrict__ B,
    const float* __restrict__ d_is,
    short* __restrict__ psT,
    float* __restrict__ P0, float* __restrict__ P1) {
    constexpr int KS = (MODE == 1) ? 2 : 1;
    constexpr int Ksub = KLEN / KS;
    constexpr int NT = Ksub / 32;
    constexpr int LDA = 40;
    __shared__ short As[2][128 * LDA];
    __shared__ short Bs[2][64 * LDA];

    const int tid = threadIdx.x;
    const int nchunk = gridDim.x >> 3;
    const int lin = blockIdx.x;
    const int swz = (lin & 7) * nchunk + (lin >> 3);
    const int col0 = (swz & 7) * 64;
    const int yp = (swz >> 3) & 63;
    const int ks = swz >> 9;
    const int row0 = yp * 128;
    const int kbase = ks * Ksub;

    const int lane = tid & 63;
    const int wv = tid >> 6;
    const int wr = wv >> 1, wc = wv & 1;
    const int l15 = lane & 15;
    const int koff = (lane >> 4) * 8;

    const int ar = tid >> 1, ak = (tid & 1) * 16;
    const float* Abase = A + (size_t)(row0 + ar) * KLEN + kbase + ak;
    const int br = tid >> 2, bk = (tid & 3) * 8;
    const short* Bbase = B + (size_t)(col0 + br) * KLEN + kbase + bk;

    float4 qa0, qa1, qa2, qa3;
    s16x8 qb;
    auto loadG = [&](int k0) {
        const float4* p = reinterpret_cast<const float4*>(Abase + k0);
        qa0 = p[0]; qa1 = p[1]; qa2 = p[2]; qa3 = p[3];
        qb = *reinterpret_cast<const s16x8*>(Bbase + k0);
    };
    auto writeL = [&](int buf) {
        const float a[16] = {qa0.x, qa0.y, qa0.z, qa0.w, qa1.x, qa1.y, qa1.z, qa1.w,
                             qa2.x, qa2.y, qa2.z, qa2.w, qa3.x, qa3.y, qa3.z, qa3.w};
        s16x8 v0, v1;
        #pragma unroll
        for (int e = 0; e < 8; ++e) { v0[e] = f2bf(a[e]); v1[e] = f2bf(a[8 + e]); }
        *reinterpret_cast<s16x8*>(&As[buf][ar * LDA + ak]) = v0;
        *reinterpret_cast<s16x8*>(&As[buf][ar * LDA + ak + 8]) = v1;
        *reinterpret_cast<s16x8*>(&Bs[buf][br * LDA + bk]) = qb;
    };

    f32x4 acc[4][2] = {};
    auto compute = [&](int buf) {
        s16x8 af[4], bfr[2];
        #pragma unroll
        for (int m = 0; m < 4; ++m)
            af[m] = *reinterpret_cast<const s16x8*>(&As[buf][(wr * 64 + m * 16 + l15) * LDA + koff]);
        #pragma unroll
        for (int n = 0; n < 2; ++n)
            bfr[n] = *reinterpret_cast<const s16x8*>(&Bs[buf][(wc * 32 + n * 16 + l15) * LDA + koff]);
        #pragma unroll
        for (int m = 0; m < 4; ++m)
            #pragma unroll
            for (int n = 0; n < 2; ++n)
                acc[m][n] = __builtin_amdgcn_mfma_f32_16x16x32_bf16(af[m], bfr[n], acc[m][n], 0, 0, 0);
    };

    loadG(0);
    writeL(0);
    __syncthreads();
    int cur = 0;
    for (int t = 0; t < NT; ++t) {
        if (t + 1 < NT) loadG((t + 1) * 32);
        compute(cur);
        if (t + 1 < NT) writeL(cur ^ 1);
        __syncthreads();
        cur ^= 1;
    }

    if (MODE == 0) {
        #pragma unroll
        for (int m = 0; m < 4; ++m) {
            const int rbase = row0 + wr * 64 + m * 16 + (lane >> 4) * 4;
            float dr[4];
            #pragma unroll
            for (int j = 0; j < 4; ++j) dr[j] = d_is[rbase + j];
            #pragma unroll
            for (int n = 0; n < 2; ++n) {
                const int col = col0 + wc * 32 + n * 16 + l15;
                u16x4 pk;
                #pragma unroll
                for (int j = 0; j < 4; ++j) pk[j] = (unsigned short)f2bf(dr[j] * acc[m][n][j]);
                *reinterpret_cast<u16x4*>(&psT[(size_t)col * NN + rbase]) = pk;
            }
        }
    } else {
        float* tgt = (ks == 0) ? P0 : P1;
        #pragma unroll
        for (int m = 0; m < 4; ++m) {
            const int rbase = row0 + wr * 64 + m * 16 + (lane >> 4) * 4;
            #pragma unroll
            for (int n = 0; n < 2; ++n) {
                const int col = col0 + wc * 32 + n * 16 + l15;
                f32x4 v = acc[m][n];
                if (ks == 0) {
                    const u16x4 sv = *reinterpret_cast<const u16x4*>(&psT[(size_t)col * NN + rbase]);
                    #pragma unroll
                    for (int j = 0; j < 4; ++j) v[j] += bf2f((short)sv[j]);
                }
                #pragma unroll
                for (int j = 0; j < 4; ++j)
                    tgt[(size_t)(rbase + j) * FOUT + col] = v[j];
            }
        }
    }
}

__global__ __launch_bounds__(256) void ep_kernel(const float* __restrict__ P0,
                                                 float* __restrict__ out,
                                                 const float* __restrict__ d_is,
                                                 const float* __restrict__ bias) {
    const size_t idx = ((size_t)blockIdx.x * 256 + threadIdx.x) * 4;
    const int row = (int)(idx >> 9);
    const int col = (int)(idx & 511);
    const float4 p0 = *reinterpret_cast<const float4*>(&P0[idx]);
    const float4 p1 = *reinterpret_cast<const float4*>(&out[idx]);
    const float4 bb = *reinterpret_cast<const float4*>(&bias[col]);
    const float dr = d_is[row];
    float4 o;
    o.x = fmaxf(dr * (p0.x + p1.x) + bb.x, 0.f);
    o.y = fmaxf(dr * (p0.y + p1.y) + bb.y, 0.f);
    o.z = fmaxf(dr * (p0.z + p1.z) + bb.z, 0.f);
    o.w = fmaxf(dr * (p0.w + p1.w) + bb.w, 0.f);
    *reinterpret_cast<float4*>(&out[idx]) = o;
}

extern "C" void kernel_launch(void* const* d_in, const int* in_sizes, int n_in,
                              void* d_out, int out_size, void* d_ws, size_t ws_size,
                              hipStream_t stream) {
    const float* x   = (const float*)d_in[0];
    const float* adj = (const float*)d_in[1];
    const float* W   = (const float*)d_in[2];
    const float* b   = (const float*)d_in[3];
    float* out = (float*)d_out;

    // Path A layout: psT | WT | xB | Pb0 | Pb1 | Pb2 | dis | adjB
    const size_t NEED = (size_t)FOUT * NN * 2 + (size_t)FOUT * FIN * 2
                      + (size_t)NN * FIN * 2 + 3ull * NN * FOUT * 2
                      + NN * 4 + (size_t)NN * NN * 2;

    if (ws_size >= NEED) {
        short* psT = (short*)d_ws;
        short* WT  = psT + (size_t)FOUT * NN;
        short* xB  = WT + (size_t)FOUT * FIN;
        short* Pb0 = xB + (size_t)NN * FIN;
        short* Pb1 = Pb0 + (size_t)NN * FOUT;
        short* Pb2 = Pb1 + (size_t)NN * FOUT;
        float* dis = (float*)(Pb2 + (size_t)NN * FOUT);
        short* adjB = (short*)(dis + NN);

        hipLaunchKernelGGL(prep_kernel, dim3(NN + 4096 + 128), dim3(256), 0, stream,
                           adj, adjB, dis, x, xB, W, WT);
        hipLaunchKernelGGL(xwg_kernel, dim3(512), dim3(256), 0, stream, xB, WT, dis, psT);
        hipLaunchKernelGGL(prop3_kernel, dim3(256), dim3(512), 131072, stream,
                           adjB, psT, Pb0, Pb1, Pb2, out);
        hipLaunchKernelGGL(ep4_kernel, dim3(4, 256), dim3(256), 0, stream,
                           Pb0, Pb1, Pb2, out, psT, dis, b);
    } else {
        short* psT = (short*)d_ws;
        short* WT  = psT + (size_t)FOUT * NN;
        float* P0  = (float*)(WT + (size_t)FOUT * FIN);
        float* dis = P0 + (size_t)NN * FOUT;

        hipLaunchKernelGGL(rowsum_kernel, dim3(NN), dim3(256), 0, stream, adj, dis);
        hipLaunchKernelGGL(wt_kernel, dim3(8, 16), dim3(256), 0, stream, W, WT);
        hipLaunchKernelGGL((gemm_kernel<FIN, 0>), dim3(512), dim3(256), 0, stream,
                           x, WT, dis, psT, nullptr, nullptr);
        hipLaunchKernelGGL((gemm_kernel<NN, 1>), dim3(1024), dim3(256), 0, stream,
                           adj, psT, dis, psT, P0, out);
        hipLaunchKernelGGL(ep_kernel, dim3(NN * FOUT / 1024), dim3(256), 0, stream,
                           P0, out, dis, b);
    }
}

// Round 9
// 189.868 us; speedup vs baseline: 6.2549x; 1.0111x over previous
//
#include <hip/hip_runtime.h>
#include <stdint.h>

#define NN 8192
#define FIN 1024
#define FOUT 512

typedef __attribute__((ext_vector_type(4))) float f32x4;
typedef __attribute__((ext_vector_type(8))) short s16x8;
typedef __attribute__((ext_vector_type(4))) unsigned short u16x4;

__device__ __forceinline__ short f2bf(float f) {
    return __builtin_bit_cast(short, static_cast<__bf16>(f));
}
__device__ __forceinline__ float bf2f(short s) {
    return (float)__builtin_bit_cast(__bf16, s);
}

// ---------- Kernel 1 (path A): fused prep ----------
// blocks [0,8192): rowsum+cvt adj->adjB ; [8192,12288): x->xB ; [12288,12416): W->WT
__global__ __launch_bounds__(256) void prep_kernel(const float* __restrict__ adj,
                                                   short* __restrict__ adjB,
                                                   float* __restrict__ d_is,
                                                   const float* __restrict__ x,
                                                   short* __restrict__ xB,
                                                   const float* __restrict__ W,
                                                   short* __restrict__ WT) {
    __shared__ float red[4];
    __shared__ float T[64][68];
    const int b = blockIdx.x;
    const int t = threadIdx.x;
    if (b < NN) {
        const int row = b;
        const float4* a = reinterpret_cast<const float4*>(adj + (size_t)row * NN);
        u16x4* ob = reinterpret_cast<u16x4*>(adjB + (size_t)row * NN);
        float s = 0.f;
        #pragma unroll 2
        for (int j = t; j < NN / 4; j += 256) {
            float4 v = a[j];
            s += (v.x + v.y) + (v.z + v.w);
            u16x4 p;
            p[0] = (unsigned short)f2bf(v.x); p[1] = (unsigned short)f2bf(v.y);
            p[2] = (unsigned short)f2bf(v.z); p[3] = (unsigned short)f2bf(v.w);
            ob[j] = p;
        }
        #pragma unroll
        for (int off = 32; off > 0; off >>= 1) s += __shfl_down(s, off, 64);
        if ((t & 63) == 0) red[t >> 6] = s;
        __syncthreads();
        if (t == 0) {
            const float d = red[0] + red[1] + red[2] + red[3] + 1.0f;
            d_is[row] = 1.0f / sqrtf(d);
        }
    } else if (b < NN + 4096) {
        const size_t i = ((size_t)(b - NN) * 256 + t) * 8;
        const float4 v0 = *reinterpret_cast<const float4*>(&x[i]);
        const float4 v1 = *reinterpret_cast<const float4*>(&x[i + 4]);
        s16x8 o;
        o[0] = f2bf(v0.x); o[1] = f2bf(v0.y); o[2] = f2bf(v0.z); o[3] = f2bf(v0.w);
        o[4] = f2bf(v1.x); o[5] = f2bf(v1.y); o[6] = f2bf(v1.z); o[7] = f2bf(v1.w);
        *reinterpret_cast<s16x8*>(&xB[i]) = o;
    } else {
        const int bid = b - NN - 4096;
        const int wc = bid & 7;
        const int wk = bid >> 3;
        const int cc = (t & 15) * 4;
        #pragma unroll
        for (int i = 0; i < 4; ++i) {
            const int rr = (t >> 4) + i * 16;
            *reinterpret_cast<float4*>(&T[rr][cc]) =
                *reinterpret_cast<const float4*>(&W[(size_t)(wk * 64 + rr) * FOUT + wc * 64 + cc]);
        }
        __syncthreads();
        const int a = t >> 2;
        const int b0 = (t & 3) * 16;
        s16x8 v0, v1;
        #pragma unroll
        for (int e = 0; e < 8; ++e) { v0[e] = f2bf(T[b0 + e][a]); v1[e] = f2bf(T[b0 + 8 + e][a]); }
        short* dst = &WT[(size_t)(wc * 64 + a) * FIN + wk * 64 + b0];
        *reinterpret_cast<s16x8*>(dst) = v0;
        *reinterpret_cast<s16x8*>(dst + 8) = v1;
    }
}

// ---------- Kernel 1B (fallback): rowsum only ----------
__global__ __launch_bounds__(256) void rowsum_kernel(const float* __restrict__ adj,
                                                     float* __restrict__ d_is) {
    const int row = blockIdx.x;
    const float4* a = reinterpret_cast<const float4*>(adj + (size_t)row * NN);
    float s = 0.f;
    #pragma unroll 4
    for (int j = threadIdx.x; j < NN / 4; j += 256) {
        float4 v = a[j];
        s += (v.x + v.y) + (v.z + v.w);
    }
    #pragma unroll
    for (int off = 32; off > 0; off >>= 1) s += __shfl_down(s, off, 64);
    __shared__ float red[4];
    if ((threadIdx.x & 63) == 0) red[threadIdx.x >> 6] = s;
    __syncthreads();
    if (threadIdx.x == 0) {
        const float d = red[0] + red[1] + red[2] + red[3] + 1.0f;
        d_is[row] = 1.0f / sqrtf(d);
    }
}

// ---------- Kernel wt (fallback) ----------
__global__ __launch_bounds__(256) void wt_kernel(const float* __restrict__ W,
                                                 short* __restrict__ WT) {
    __shared__ float T[64][68];
    const int wc = blockIdx.x;
    const int wk = blockIdx.y;
    const int t = threadIdx.x;
    const int cc = (t & 15) * 4;
    #pragma unroll
    for (int i = 0; i < 4; ++i) {
        const int rr = (t >> 4) + i * 16;
        *reinterpret_cast<float4*>(&T[rr][cc]) =
            *reinterpret_cast<const float4*>(&W[(size_t)(wk * 64 + rr) * FOUT + wc * 64 + cc]);
    }
    __syncthreads();
    const int a = t >> 2;
    const int b0 = (t & 3) * 16;
    s16x8 v0, v1;
    #pragma unroll
    for (int e = 0; e < 8; ++e) { v0[e] = f2bf(T[b0 + e][a]); v1[e] = f2bf(T[b0 + 8 + e][a]); }
    short* dst = &WT[(size_t)(wc * 64 + a) * FIN + wk * 64 + b0];
    *reinterpret_cast<s16x8*>(dst) = v0;
    *reinterpret_cast<s16x8*>(dst + 8) = v1;
}

// ---------- Kernel 2: xwg — glds-staged bf16 GEMM, counted-vmcnt ----------
__global__ __launch_bounds__(256, 4) void xwg_kernel(const short* __restrict__ xB,
                                                     const short* __restrict__ WT,
                                                     const float* __restrict__ d_is,
                                                     short* __restrict__ psT) {
    constexpr int NT = FIN / 32;  // 32
    __shared__ short As[2][4096];
    __shared__ short Bs[2][2048];

    const int tid = threadIdx.x;
    const int lin = blockIdx.x;
    const int swz = (lin & 7) * 64 + (lin >> 3);
    const int col0 = (swz & 7) * 64;
    const int row0 = (swz >> 3) * 128;

    const int lane = tid & 63;
    const int wv = tid >> 6;
    const int wr = wv >> 1, wc = wv & 1;
    const int l15 = lane & 15;
    const int kq = lane >> 4;
    const int xorv = (l15 & 12) << 2;

    int arow[2], acoff[2];
    #pragma unroll
    for (int i = 0; i < 2; ++i) {
        const int slot = i * 256 + tid;
        const int P = (slot << 4) ^ (slot & 48);
        arow[i] = P >> 6;
        acoff[i] = (P & 63) >> 1;
    }
    const short* Ab = xB + (size_t)row0 * FIN;
    const short* Bb = WT + (size_t)col0 * FIN;

    auto stage = [&](int buf, int k0) {
        #pragma unroll
        for (int i = 0; i < 2; ++i) {
            const short* src = Ab + (size_t)arow[i] * FIN + k0 + acoff[i];
            short* dst = &As[buf][(i * 256 + (tid & 192)) * 8];
            __builtin_amdgcn_global_load_lds(
                (const __attribute__((address_space(1))) unsigned int*)src,
                (__attribute__((address_space(3))) unsigned int*)dst, 16, 0, 0);
        }
        {
            const short* src = Bb + (size_t)arow[0] * FIN + k0 + acoff[0];
            short* dst = &Bs[buf][(tid & 192) * 8];
            __builtin_amdgcn_global_load_lds(
                (const __attribute__((address_space(1))) unsigned int*)src,
                (__attribute__((address_space(3))) unsigned int*)dst, 16, 0, 0);
        }
    };

    f32x4 acc[4][2] = {};
    auto compute = [&](int buf) {
        s16x8 af[4], bfr[2];
        #pragma unroll
        for (int m = 0; m < 4; ++m) {
            const int byteoff = ((wr * 64 + m * 16 + l15) * 64 + kq * 16) ^ xorv;
            af[m] = *reinterpret_cast<const s16x8*>(&As[buf][byteoff >> 1]);
        }
        #pragma unroll
        for (int n = 0; n < 2; ++n) {
            const int byteoff = ((wc * 32 + n * 16 + l15) * 64 + kq * 16) ^ xorv;
            bfr[n] = *reinterpret_cast<const s16x8*>(&Bs[buf][byteoff >> 1]);
        }
        #pragma unroll
        for (int m = 0; m < 4; ++m)
            #pragma unroll
            for (int n = 0; n < 2; ++n)
                acc[m][n] = __builtin_amdgcn_mfma_f32_16x16x32_bf16(af[m], bfr[n], acc[m][n], 0, 0, 0);
    };

    stage(0, 0);
    stage(1, 32);
    int cur = 0;
    #pragma unroll 1
    for (int t = 0; t < NT; ++t) {
        if (t < NT - 1) {
            asm volatile("s_waitcnt vmcnt(3)" ::: "memory");
        } else {
            asm volatile("s_waitcnt vmcnt(0)" ::: "memory");
        }
        __builtin_amdgcn_s_barrier();
        compute(cur);
        if (t + 2 < NT) {
            __builtin_amdgcn_s_barrier();
            stage(cur, (t + 2) * 32);
        }
        cur ^= 1;
    }

    #pragma unroll
    for (int m = 0; m < 4; ++m) {
        const int rbase = row0 + wr * 64 + m * 16 + kq * 4;
        float dr[4];
        #pragma unroll
        for (int j = 0; j < 4; ++j) dr[j] = d_is[rbase + j];
        #pragma unroll
        for (int n = 0; n < 2; ++n) {
            const int col = col0 + wc * 32 + n * 16 + l15;
            u16x4 pk;
            #pragma unroll
            for (int j = 0; j < 4; ++j) pk[j] = (unsigned short)f2bf(dr[j] * acc[m][n][j]);
            *reinterpret_cast<u16x4*>(&psT[(size_t)col * NN + rbase]) = pk;
        }
    }
}

// ---------- Kernel 3: prop3 — 256x256 8-phase, counted vmcnt, split-K=4 ----------
// A = adjB [8192][8192] bf16, B = psT [512][8192] bf16. 512 thr, 8 waves (2x4).
// LDS 128 KB dynamic: 2 buf x { A[2 kh][256r][32k] | B[2 kh][256r][32k] }.
__global__ __launch_bounds__(512, 1) void prop3_kernel(
    const short* __restrict__ adjB, const short* __restrict__ psT,
    short* __restrict__ Pb0, short* __restrict__ Pb1,
    short* __restrict__ Pb2, short* __restrict__ Pb3) {
    extern __shared__ short L[];  // 65536 shorts = 128 KB

    const int tid = threadIdx.x;
    const int lin = blockIdx.x;
    const int swz = (lin & 7) * 32 + (lin >> 3);   // bijective XCD chunking (256 = 8*32)
    const int col0 = (swz & 1) * 256;
    const int ks = (swz >> 1) & 3;
    const int row0 = (swz >> 3) * 256;

    const int lane = tid & 63;
    const int wv = tid >> 6;        // 0..7
    const int wr = wv >> 2;         // 0..1: row half (128 rows)
    const int wc = wv & 3;          // 0..3: col quarter (64 cols)
    const int l15 = lane & 15;
    const int kq = lane >> 4;
    const int xorv = (l15 & 12) << 2;

    // staging source indices (inverse-swizzled): slot = i*512 + tid over a 16 KB half
    int srow[2], scol[2];
    #pragma unroll
    for (int i = 0; i < 2; ++i) {
        const int slot = i * 512 + tid;
        const int P = (slot << 4) ^ (slot & 48);
        srow[i] = P >> 6;          // 0..255
        scol[i] = (P & 63) >> 1;   // 0..31
    }
    const size_t kbase = (size_t)ks * 2048;
    const short* Ab = adjB + (size_t)row0 * NN + kbase;
    const short* Bb = psT + (size_t)col0 * NN + kbase;

    // stage one half-tile (16 KB): op 0=A,1=B; k-half kh of tile t into buffer buf
    auto stageH = [&](int buf, int op, int kh, int t) {
        const short* s0 = op ? Bb : Ab;
        const int k0 = t * 64 + kh * 32;
        short* base = &L[buf * 32768 + op * 16384 + kh * 8192];
        #pragma unroll
        for (int i = 0; i < 2; ++i) {
            const short* src = s0 + (size_t)srow[i] * NN + k0 + scol[i];
            short* dst = base + (i * 512 + (tid & 448)) * 8;
            __builtin_amdgcn_global_load_lds(
                (const __attribute__((address_space(1))) unsigned int*)src,
                (__attribute__((address_space(3))) unsigned int*)dst, 16, 0, 0);
        }
    };

    f32x4 acc[8][4] = {};

#define LDFRAG(BASE, ROW) \
    (*reinterpret_cast<const s16x8*>(&(BASE)[((((ROW) * 64 + kq * 16)) ^ xorv) >> 1]))

#define PHASE(BUF, KH, QM, STAGE_STMT, VM_STMT)                                     \
    do {                                                                            \
        const short* Ah_ = &L[(BUF) * 32768 + (KH) * 8192];                         \
        const short* Bh_ = &L[(BUF) * 32768 + 16384 + (KH) * 8192];                 \
        s16x8 af_[4], bg_[4];                                                       \
        _Pragma("unroll")                                                           \
        for (int m = 0; m < 4; ++m)                                                 \
            af_[m] = LDFRAG(Ah_, wr * 128 + (QM) * 64 + m * 16 + l15);              \
        _Pragma("unroll")                                                           \
        for (int n = 0; n < 4; ++n)                                                 \
            bg_[n] = LDFRAG(Bh_, wc * 64 + n * 16 + l15);                           \
        STAGE_STMT;                                                                 \
        asm volatile("" ::: "memory");                                              \
        __builtin_amdgcn_s_barrier();                                               \
        __builtin_amdgcn_s_setprio(1);                                              \
        _Pragma("unroll")                                                           \
        for (int m = 0; m < 4; ++m)                                                 \
            _Pragma("unroll")                                                       \
            for (int n = 0; n < 4; ++n)                                             \
                acc[(QM) * 4 + m][n] = __builtin_amdgcn_mfma_f32_16x16x32_bf16(     \
                    af_[m], bg_[n], acc[(QM) * 4 + m][n], 0, 0, 0);                 \
        __builtin_amdgcn_s_setprio(0);                                              \
        VM_STMT;                                                                    \
        asm volatile("" ::: "memory");                                              \
        __builtin_amdgcn_s_barrier();                                               \
    } while (0)

#define VM4 asm volatile("s_waitcnt vmcnt(4)" ::: "memory")
#define VM0 asm volatile("s_waitcnt vmcnt(0)" ::: "memory")

    // prologue: tile0 all 4 halves + tile1 {A0,B0}  (12 vmem instr/wave)
    stageH(0, 0, 0, 0); stageH(0, 1, 0, 0);
    stageH(0, 0, 1, 0); stageH(0, 1, 1, 0);
    stageH(1, 0, 0, 1); stageH(1, 1, 0, 1);
    asm volatile("s_waitcnt vmcnt(8)" ::: "memory");   // tile0 {A0,B0} landed
    __builtin_amdgcn_s_barrier();

    // t = 0 (buf 0): t1 {A0,B0} pre-staged; issue t1 {A1,B1} at phases 2,3
    PHASE(0, 0, 0, (void)0,             (void)0);
    PHASE(0, 0, 1, (void)0,             VM4);
    PHASE(0, 1, 0, stageH(1, 0, 1, 1),  (void)0);
    PHASE(0, 1, 1, stageH(1, 1, 1, 1),  VM4);

    // steady t = 1..30
    #pragma unroll 1
    for (int t = 1; t <= 30; ++t) {
        const int buf = t & 1, nb = buf ^ 1, tn = t + 1;
        PHASE(buf, 0, 0, stageH(nb, 0, 0, tn), (void)0);
        PHASE(buf, 0, 1, stageH(nb, 1, 0, tn), VM4);
        PHASE(buf, 1, 0, stageH(nb, 0, 1, tn), (void)0);
        PHASE(buf, 1, 1, stageH(nb, 1, 1, tn), VM4);
    }

    // t = 31 (buf 1): no more staging
    PHASE(1, 0, 0, (void)0, (void)0);
    PHASE(1, 0, 1, (void)0, VM0);
    PHASE(1, 1, 0, (void)0, (void)0);
    PHASE(1, 1, 1, (void)0, (void)0);

    // epilogue: bf16 partials (C/D map: col = lane&15, row = kq*4 + j)
    {
        short* Pt = (ks == 0) ? Pb0 : (ks == 1) ? Pb1 : (ks == 2) ? Pb2 : Pb3;
        #pragma unroll
        for (int mi = 0; mi < 8; ++mi) {
            const int rbase = row0 + wr * 128 + mi * 16 + kq * 4;
            #pragma unroll
            for (int n = 0; n < 4; ++n) {
                const int col = col0 + wc * 64 + n * 16 + l15;
                #pragma unroll
                for (int j = 0; j < 4; ++j)
                    Pt[(size_t)(rbase + j) * FOUT + col] = f2bf(acc[mi][n][j]);
            }
        }
    }
#undef PHASE
#undef LDFRAG
#undef VM4
#undef VM0
}

// ---------- Kernel 4: out = relu(d*(Pb0+Pb1+Pb2+Pb3 + psT^T) + b) ----------
__global__ __launch_bounds__(256) void ep4_kernel(
    const short* __restrict__ Pb0, const short* __restrict__ Pb1,
    const short* __restrict__ Pb2, const short* __restrict__ Pb3,
    float* __restrict__ out,
    const short* __restrict__ psT, const float* __restrict__ d_is,
    const float* __restrict__ bias) {
    const int col0 = blockIdx.x * 128;
    const int row0 = blockIdx.y * 32;
    const int t = threadIdx.x;
    const int c = col0 + (t & 31) * 4;
    const float4 bb = *reinterpret_cast<const float4*>(&bias[c]);
    #pragma unroll
    for (int it = 0; it < 4; ++it) {
        const int r = row0 + (t >> 5) + it * 8;
        const size_t idx = (size_t)r * FOUT + c;
        const u16x4 a = *reinterpret_cast<const u16x4*>(&Pb0[idx]);
        const u16x4 b4 = *reinterpret_cast<const u16x4*>(&Pb1[idx]);
        const u16x4 c4 = *reinterpret_cast<const u16x4*>(&Pb2[idx]);
        const u16x4 d4 = *reinterpret_cast<const u16x4*>(&Pb3[idx]);
        const float dr = d_is[r];
        float s[4], o4[4];
        #pragma unroll
        for (int j = 0; j < 4; ++j) s[j] = bf2f(psT[(size_t)(c + j) * NN + r]);
        const float bbv[4] = {bb.x, bb.y, bb.z, bb.w};
        #pragma unroll
        for (int j = 0; j < 4; ++j) {
            const float sum = ((bf2f((short)a[j]) + bf2f((short)b4[j])) +
                               (bf2f((short)c4[j]) + bf2f((short)d4[j]))) + s[j];
            o4[j] = fmaxf(dr * sum + bbv[j], 0.f);
        }
        float4 o = {o4[0], o4[1], o4[2], o4[3]};
        *reinterpret_cast<float4*>(&out[idx]) = o;
    }
}

// ---------- Fallback kernels (small-ws path) ----------
template<int KLEN, int MODE>
__global__ __launch_bounds__(256, 4) void gemm_kernel(
    const float* __restrict__ A, const short* __restrict__ B,
    const float* __restrict__ d_is,
    short* __restrict__ psT,
    float* __restrict__ P0, float* __restrict__ P1) {
    constexpr int KS = (MODE == 1) ? 2 : 1;
    constexpr int Ksub = KLEN / KS;
    constexpr int NT = Ksub / 32;
    constexpr int LDA = 40;
    __shared__ short As[2][128 * LDA];
    __shared__ short Bs[2][64 * LDA];

    const int tid = threadIdx.x;
    const int nchunk = gridDim.x >> 3;
    const int lin = blockIdx.x;
    const int swz = (lin & 7) * nchunk + (lin >> 3);
    const int col0 = (swz & 7) * 64;
    const int yp = (swz >> 3) & 63;
    const int ks = swz >> 9;
    const int row0 = yp * 128;
    const int kbase = ks * Ksub;

    const int lane = tid & 63;
    const int wv = tid >> 6;
    const int wr = wv >> 1, wc = wv & 1;
    const int l15 = lane & 15;
    const int koff = (lane >> 4) * 8;

    const int ar = tid >> 1, ak = (tid & 1) * 16;
    const float* Abase = A + (size_t)(row0 + ar) * KLEN + kbase + ak;
    const int br = tid >> 2, bk = (tid & 3) * 8;
    const short* Bbase = B + (size_t)(col0 + br) * KLEN + kbase + bk;

    float4 qa0, qa1, qa2, qa3;
    s16x8 qb;
    auto loadG = [&](int k0) {
        const float4* p = reinterpret_cast<const float4*>(Abase + k0);
        qa0 = p[0]; qa1 = p[1]; qa2 = p[2]; qa3 = p[3];
        qb = *reinterpret_cast<const s16x8*>(Bbase + k0);
    };
    auto writeL = [&](int buf) {
        const float a[16] = {qa0.x, qa0.y, qa0.z, qa0.w, qa1.x, qa1.y, qa1.z, qa1.w,
                             qa2.x, qa2.y, qa2.z, qa2.w, qa3.x, qa3.y, qa3.z, qa3.w};
        s16x8 v0, v1;
        #pragma unroll
        for (int e = 0; e < 8; ++e) { v0[e] = f2bf(a[e]); v1[e] = f2bf(a[8 + e]); }
        *reinterpret_cast<s16x8*>(&As[buf][ar * LDA + ak]) = v0;
        *reinterpret_cast<s16x8*>(&As[buf][ar * LDA + ak + 8]) = v1;
        *reinterpret_cast<s16x8*>(&Bs[buf][br * LDA + bk]) = qb;
    };

    f32x4 acc[4][2] = {};
    auto compute = [&](int buf) {
        s16x8 af[4], bfr[2];
        #pragma unroll
        for (int m = 0; m < 4; ++m)
            af[m] = *reinterpret_cast<const s16x8*>(&As[buf][(wr * 64 + m * 16 + l15) * LDA + koff]);
        #pragma unroll
        for (int n = 0; n < 2; ++n)
            bfr[n] = *reinterpret_cast<const s16x8*>(&Bs[buf][(wc * 32 + n * 16 + l15) * LDA + koff]);
        #pragma unroll
        for (int m = 0; m < 4; ++m)
            #pragma unroll
            for (int n = 0; n < 2; ++n)
                acc[m][n] = __builtin_amdgcn_mfma_f32_16x16x32_bf16(af[m], bfr[n], acc[m][n], 0, 0, 0);
    };

    loadG(0);
    writeL(0);
    __syncthreads();
    int cur = 0;
    for (int t = 0; t < NT; ++t) {
        if (t + 1 < NT) loadG((t + 1) * 32);
        compute(cur);
        if (t + 1 < NT) writeL(cur ^ 1);
        __syncthreads();
        cur ^= 1;
    }

    if (MODE == 0) {
        #pragma unroll
        for (int m = 0; m < 4; ++m) {
            const int rbase = row0 + wr * 64 + m * 16 + (lane >> 4) * 4;
            float dr[4];
            #pragma unroll
            for (int j = 0; j < 4; ++j) dr[j] = d_is[rbase + j];
            #pragma unroll
            for (int n = 0; n < 2; ++n) {
                const int col = col0 + wc * 32 + n * 16 + l15;
                u16x4 pk;
                #pragma unroll
                for (int j = 0; j < 4; ++j) pk[j] = (unsigned short)f2bf(dr[j] * acc[m][n][j]);
                *reinterpret_cast<u16x4*>(&psT[(size_t)col * NN + rbase]) = pk;
            }
        }
    } else {
        float* tgt = (ks == 0) ? P0 : P1;
        #pragma unroll
        for (int m = 0; m < 4; ++m) {
            const int rbase = row0 + wr * 64 + m * 16 + (lane >> 4) * 4;
            #pragma unroll
            for (int n = 0; n < 2; ++n) {
                const int col = col0 + wc * 32 + n * 16 + l15;
                f32x4 v = acc[m][n];
                if (ks == 0) {
                    const u16x4 sv = *reinterpret_cast<const u16x4*>(&psT[(size_t)col * NN + rbase]);
                    #pragma unroll
                    for (int j = 0; j < 4; ++j) v[j] += bf2f((short)sv[j]);
                }
                #pragma unroll
                for (int j = 0; j < 4; ++j)
                    tgt[(size_t)(rbase + j) * FOUT + col] = v[j];
            }
        }
    }
}

__global__ __launch_bounds__(256) void ep_kernel(const float* __restrict__ P0,
                                                 float* __restrict__ out,
                                                 const float* __restrict__ d_is,
                                                 const float* __restrict__ bias) {
    const size_t idx = ((size_t)blockIdx.x * 256 + threadIdx.x) * 4;
    const int row = (int)(idx >> 9);
    const int col = (int)(idx & 511);
    const float4 p0 = *reinterpret_cast<const float4*>(&P0[idx]);
    const float4 p1 = *reinterpret_cast<const float4*>(&out[idx]);
    const float4 bb = *reinterpret_cast<const float4*>(&bias[col]);
    const float dr = d_is[row];
    float4 o;
    o.x = fmaxf(dr * (p0.x + p1.x) + bb.x, 0.f);
    o.y = fmaxf(dr * (p0.y + p1.y) + bb.y, 0.f);
    o.z = fmaxf(dr * (p0.z + p1.z) + bb.z, 0.f);
    o.w = fmaxf(dr * (p0.w + p1.w) + bb.w, 0.f);
    *reinterpret_cast<float4*>(&out[idx]) = o;
}

extern "C" void kernel_launch(void* const* d_in, const int* in_sizes, int n_in,
                              void* d_out, int out_size, void* d_ws, size_t ws_size,
                              hipStream_t stream) {
    const float* x   = (const float*)d_in[0];
    const float* adj = (const float*)d_in[1];
    const float* W   = (const float*)d_in[2];
    const float* b   = (const float*)d_in[3];
    float* out = (float*)d_out;

    // Path A layout: psT | WT | xB | Pb0..Pb3 | dis | adjB
    const size_t NEED = (size_t)FOUT * NN * 2 + (size_t)FOUT * FIN * 2
                      + (size_t)NN * FIN * 2 + 4ull * NN * FOUT * 2
                      + NN * 4 + (size_t)NN * NN * 2;

    if (ws_size >= NEED) {
        short* psT = (short*)d_ws;
        short* WT  = psT + (size_t)FOUT * NN;
        short* xB  = WT + (size_t)FOUT * FIN;
        short* Pb0 = xB + (size_t)NN * FIN;
        short* Pb1 = Pb0 + (size_t)NN * FOUT;
        short* Pb2 = Pb1 + (size_t)NN * FOUT;
        short* Pb3 = Pb2 + (size_t)NN * FOUT;
        float* dis = (float*)(Pb3 + (size_t)NN * FOUT);
        short* adjB = (short*)(dis + NN);

        hipLaunchKernelGGL(prep_kernel, dim3(NN + 4096 + 128), dim3(256), 0, stream,
                           adj, adjB, dis, x, xB, W, WT);
        hipLaunchKernelGGL(xwg_kernel, dim3(512), dim3(256), 0, stream, xB, WT, dis, psT);
        hipLaunchKernelGGL(prop3_kernel, dim3(256), dim3(512), 131072, stream,
                           adjB, psT, Pb0, Pb1, Pb2, Pb3);
        hipLaunchKernelGGL(ep4_kernel, dim3(4, 256), dim3(256), 0, stream,
                           Pb0, Pb1, Pb2, Pb3, out, psT, dis, b);
    } else {
        short* psT = (short*)d_ws;
        short* WT  = psT + (size_t)FOUT * NN;
        float* P0  = (float*)(WT + (size_t)FOUT * FIN);
        float* dis = P0 + (size_t)NN * FOUT;

        hipLaunchKernelGGL(rowsum_kernel, dim3(NN), dim3(256), 0, stream, adj, dis);
        hipLaunchKernelGGL(wt_kernel, dim3(8, 16), dim3(256), 0, stream, W, WT);
        hipLaunchKernelGGL((gemm_kernel<FIN, 0>), dim3(512), dim3(256), 0, stream,
                           x, WT, dis, psT, nullptr, nullptr);
        hipLaunchKernelGGL((gemm_kernel<NN, 1>), dim3(1024), dim3(256), 0, stream,
                           adj, psT, dis, psT, P0, out);
        hipLaunchKernelGGL(ep_kernel, dim3(NN * FOUT / 1024), dim3(256), 0, stream,
                           P0, out, dis, b);
    }
}